// Round 5
// baseline (705.164 us; speedup 1.0000x reference)
//
#include <hip/hip_runtime.h>
#include <hip/hip_bf16.h>
#include <math.h>

// Problem constants (from reference setup_inputs)
constexpr int kN = 32768;   // nodes
constexpr int kE = 262144;  // edges
constexpr int kD = 256;     // hidden
constexpr int kH = 4;       // heads
constexpr int kC = 64;      // head dim
constexpr int kG = 32;      // graphs
constexpr float kScale = 0.125f;  // 1/sqrt(64)
constexpr float kEps = 1e-5f;

typedef __attribute__((ext_vector_type(8))) short short8;     // 8 bf16 = 4 VGPR
typedef __attribute__((ext_vector_type(4))) float floatx4;

__device__ inline unsigned short f2bf(float f) {
  union { __hip_bfloat16 b; unsigned short u; } cv;
  cv.b = __float2bfloat16(f);
  return cv.u;
}

__device__ inline float bf2f(unsigned int u16) {
  union { float f; unsigned int i; } c;
  c.i = u16 << 16;
  return c.f;
}

__device__ inline void async_copy16(const void* g, void* l) {
  __builtin_amdgcn_global_load_lds(
      (const __attribute__((address_space(1))) void*)g,
      (__attribute__((address_space(3))) void*)l, 16, 0, 0);
}

// ---------------------------------------------------------------- sort by dst
__global__ __launch_bounds__(256) void hist_kernel(const int* __restrict__ ei,
                                                   int* __restrict__ counts) {
  int e = blockIdx.x * 256 + threadIdx.x;
  atomicAdd(&counts[ei[kE + e]], 1);
}

__global__ __launch_bounds__(1024) void scan_kernel(const int* __restrict__ counts,
                                                    int* __restrict__ row_start,
                                                    int* __restrict__ cursor) {
  __shared__ int wsums[16];
  int t = threadIdx.x;
  int base_i = t * 32;
  int loc[32];
  int run = 0;
#pragma unroll
  for (int j = 0; j < 32; ++j) { loc[j] = run; run += counts[base_i + j]; }
  int incl = run;
  int lane = t & 63;
#pragma unroll
  for (int d = 1; d < 64; d <<= 1) {
    int v = __shfl_up(incl, d, 64);
    if (lane >= d) incl += v;
  }
  if (lane == 63) wsums[t >> 6] = incl;
  __syncthreads();
  if (t == 0) {
    int acc = 0;
    for (int w = 0; w < 16; ++w) { int tmp = wsums[w]; wsums[w] = acc; acc += tmp; }
  }
  __syncthreads();
  int base = wsums[t >> 6] + (incl - run);
#pragma unroll
  for (int j = 0; j < 32; ++j) {
    int v = base + loc[j];
    row_start[base_i + j] = v;
    cursor[base_i + j] = v;
  }
  if (t == 0) row_start[kN] = kE;
}

__global__ __launch_bounds__(256) void scatter_kernel(const int* __restrict__ ei,
                                                      int* __restrict__ cursor,
                                                      int* __restrict__ perm) {
  int e = blockIdx.x * 256 + threadIdx.x;
  int d = ei[kE + e];
  int pos = atomicAdd(&cursor[d], 1);
  perm[pos] = e;
}

// ---------------------------------------------------------------- weight transpose + bf16
// Wt[slot][n][k] = W[slot][k][n] as bf16 ; slot = l*4 + {q,k,v,skip}
__global__ __launch_bounds__(256) void transpose_w_kernel(
    const float* __restrict__ Wq, const float* __restrict__ Wk,
    const float* __restrict__ Wv, const float* __restrict__ Ws,
    __hip_bfloat16* __restrict__ Wt) {
  __shared__ float T[32][33];
  int kt = blockIdx.x, nt = blockIdx.y, slot = blockIdx.z;
  int l = slot >> 2, mat = slot & 3;
  const float* src;
  if (mat == 0) src = Wq; else if (mat == 1) src = Wk;
  else if (mat == 2) src = Wv; else src = Ws;
  src += (size_t)l * 65536;
  int tid = threadIdx.x;
#pragma unroll
  for (int i = 0; i < 4; ++i) {
    int idx = tid + i * 256;
    int r = idx >> 5, c = idx & 31;
    T[r][c] = src[(size_t)(kt * 32 + r) * 256 + nt * 32 + c];
  }
  __syncthreads();
  __hip_bfloat16* dst = Wt + (size_t)slot * 65536;
#pragma unroll
  for (int i = 0; i < 4; ++i) {
    int idx = tid + i * 256;
    int r = idx >> 5, c = idx & 31;
    dst[(size_t)(nt * 32 + r) * 256 + kt * 32 + c] = __float2bfloat16(T[c][r]);
  }
}

// ---------------------------------------------------------------- encoder (bf16 only)
__global__ __launch_bounds__(256) void enc_kernel(const float* __restrict__ X,
                                                  const float* __restrict__ encW,
                                                  const float* __restrict__ encb,
                                                  __hip_bfloat16* __restrict__ H16) {
  int idx = blockIdx.x * 256 + threadIdx.x;  // over kN*64 float4
  int n = idx >> 6;
  int q = idx & 63;
  const float4* W4 = (const float4*)encW;
  float4 w0 = W4[q];
  float4 w1 = W4[64 + q];
  float4 bb = ((const float4*)encb)[q];
  float x0 = X[2 * n], x1 = X[2 * n + 1];
  float4 r;
  r.x = fmaf(x0, w0.x, fmaf(x1, w1.x, bb.x));
  r.y = fmaf(x0, w0.y, fmaf(x1, w1.y, bb.y));
  r.z = fmaf(x0, w0.z, fmaf(x1, w1.z, bb.z));
  r.w = fmaf(x0, w0.w, fmaf(x1, w1.w, bb.w));
  ushort4 rb;
  rb.x = f2bf(r.x); rb.y = f2bf(r.y); rb.z = f2bf(r.z); rb.w = f2bf(r.w);
  ((ushort4*)H16)[idx] = rb;
}

// ---------------------------------------------------------------- fused 4-GEMM (bf16 MFMA)
// Y = H @ W + b.  Q -> bf16 row buffer; Xr -> fp32; K,V -> interleaved bf16 KV:
// KV[node] is 1024B: chunk c (c=0..63) = { k[4c..4c+3] bf16, v[4c..4c+3] bf16 }.
__global__ __launch_bounds__(256) void gemm4_mfma(
    const __hip_bfloat16* __restrict__ H16,
    const __hip_bfloat16* __restrict__ Wt,  // 4 slots for this layer
    const float* __restrict__ bq, const float* __restrict__ bk,
    const float* __restrict__ bv, const float* __restrict__ bs,
    unsigned short* __restrict__ Q16, unsigned short* __restrict__ KV,
    float* __restrict__ Os) {
  int cb = blockIdx.x;           // 0..7 : (matrix, col-half)
  int m0 = blockIdx.y * 128;
  int wi = cb >> 1;
  int col0 = (cb & 1) * 128;
  const __hip_bfloat16* Wm = Wt + (size_t)wi * 65536;
  const float* bias;
  if (wi == 0)      bias = bq;
  else if (wi == 1) bias = bk;
  else if (wi == 2) bias = bv;
  else              bias = bs;

  __shared__ __align__(16) __hip_bfloat16 As[128 * 32];  // [m][k] row-major
  __shared__ __align__(16) __hip_bfloat16 Bs[128 * 32];  // [n][k] row-major

  int tid = threadIdx.x;
  int w = tid >> 6, lane = tid & 63;
  int wm = w & 1, wn = w >> 1;

  floatx4 acc[4][4];
#pragma unroll
  for (int i = 0; i < 4; ++i)
#pragma unroll
    for (int j = 0; j < 4; ++j) acc[i][j] = (floatx4){0.f, 0.f, 0.f, 0.f};

  int srow = lane >> 2;          // 0..15 (staging row within 16-row segment)
  int schunk = (lane & 3) * 8;   // 0,8,16,24 (bf16 elements)
  int arow = lane & 15, aq = lane >> 4;

  for (int kc = 0; kc < 256; kc += 32) {
#pragma unroll
    for (int t = 0; t < 2; ++t) {
      int s = w * 2 + t;  // segment 0..7 (16 rows each)
      const __hip_bfloat16* gA =
          H16 + (size_t)(m0 + s * 16 + srow) * 256 + kc + schunk;
      async_copy16(gA, (void*)(As + s * 512));
      const __hip_bfloat16* gB =
          Wm + (size_t)(col0 + s * 16 + srow) * 256 + kc + schunk;
      async_copy16(gB, (void*)(Bs + s * 512));
    }
    __syncthreads();
    short8 af[4], bf[4];
#pragma unroll
    for (int mi = 0; mi < 4; ++mi)
      af[mi] = *(const short8*)&As[(wm * 64 + mi * 16 + arow) * 32 + aq * 8];
#pragma unroll
    for (int ni = 0; ni < 4; ++ni)
      bf[ni] = *(const short8*)&Bs[(wn * 64 + ni * 16 + arow) * 32 + aq * 8];
#pragma unroll
    for (int mi = 0; mi < 4; ++mi)
#pragma unroll
      for (int ni = 0; ni < 4; ++ni)
        acc[mi][ni] = __builtin_amdgcn_mfma_f32_16x16x32_bf16(
            af[mi], bf[ni], acc[mi][ni], 0, 0, 0);
    __syncthreads();
  }

  // epilogue: C/D layout col=lane&15, row=(lane>>4)*4+reg
  int col = lane & 15, rq = (lane >> 4) * 4;
  if (wi == 3) {
#pragma unroll
    for (int ni = 0; ni < 4; ++ni) {
      int ccol = col0 + wn * 64 + ni * 16 + col;
      float bvv = bias[ccol];
#pragma unroll
      for (int mi = 0; mi < 4; ++mi) {
        int rbase = m0 + wm * 64 + mi * 16 + rq;
#pragma unroll
        for (int r = 0; r < 4; ++r)
          Os[(size_t)(rbase + r) * 256 + ccol] = acc[mi][ni][r] + bvv;
      }
    }
  } else if (wi == 0) {
#pragma unroll
    for (int ni = 0; ni < 4; ++ni) {
      int ccol = col0 + wn * 64 + ni * 16 + col;
      float bvv = bias[ccol];
#pragma unroll
      for (int mi = 0; mi < 4; ++mi) {
        int rbase = m0 + wm * 64 + mi * 16 + rq;
#pragma unroll
        for (int r = 0; r < 4; ++r)
          Q16[(size_t)(rbase + r) * 256 + ccol] = f2bf(acc[mi][ni][r] + bvv);
      }
    }
  } else {
    int off = (wi == 2) ? 4 : 0;  // K in first half of chunk, V in second
#pragma unroll
    for (int ni = 0; ni < 4; ++ni) {
      int ccol = col0 + wn * 64 + ni * 16 + col;
      float bvv = bias[ccol];
      size_t cofs = (size_t)(ccol >> 2) * 8 + off + (ccol & 3);
#pragma unroll
      for (int mi = 0; mi < 4; ++mi) {
        int rbase = m0 + wm * 64 + mi * 16 + rq;
#pragma unroll
        for (int r = 0; r < 4; ++r)
          KV[(size_t)(rbase + r) * 512 + cofs] = f2bf(acc[mi][ni][r] + bvv);
      }
    }
  }
}

// ---------------------------------------------------------------- fused attention + beta + BN stats
// one wave per dst node; lane L owns channels 4L..4L+3. Lane-parallel edge
// metadata preload + 2 interleaved softmax states (even/odd edges), depth-2
// prefetch each -> ~4 outstanding KV gathers. Epilogue computes beta-gated
// skip, writes h (fp32) and accumulates BN sum/sumsq via LDS + atomics.
__global__ __launch_bounds__(256) void attn_fused_kernel(
    const ushort4* __restrict__ Q16,   // [N][64] bf16 quads
    const uint4* __restrict__ KV,
    const float* __restrict__ eattr, const float* __restrict__ WeL,
    const int* __restrict__ ei, const int* __restrict__ perm,
    const int* __restrict__ row_start,
    const float* __restrict__ Xr, const float* __restrict__ Wb,
    float* __restrict__ Hb, float* __restrict__ bnsum,
    float* __restrict__ bnsq) {
  __shared__ float red[4][256];
  int tid = threadIdx.x;
  int w = tid >> 6, lane = tid & 63;
  int wid = blockIdx.x * 4 + w;

  ushort4 qr = Q16[(size_t)wid * 64 + lane];
  float q0 = bf2f(qr.x), q1 = bf2f(qr.y), q2 = bf2f(qr.z), q3 = bf2f(qr.w);
  float4 we4 = ((const float4*)WeL)[lane];
  int s0 = row_start[wid], s1 = row_start[wid + 1];

  float mA = -1e30f, lA = 0.f, mB = -1e30f, lB = 0.f;
  float4 aA = {0.f, 0.f, 0.f, 0.f}, aB = {0.f, 0.f, 0.f, 0.f};

  for (int base = s0; base < s1; base += 64) {
    int cnt = min(64, s1 - base);
    int i = base + lane;
    int sN = 0; float eaN = 0.f;
    if (i < s1) {
      int e = perm[i];
      sN = ei[e];
      eaN = eattr[e];
    }
    uint4 r0 = {0, 0, 0, 0}, r1 = {0, 0, 0, 0};
    float e0 = 0.f, e1 = 0.f;
    {
      int s = __shfl(sN, 0, 64);
      e0 = __shfl(eaN, 0, 64);
      r0 = KV[(size_t)s * 64 + lane];
    }
    if (cnt > 1) {
      int s = __shfl(sN, 1, 64);
      e1 = __shfl(eaN, 1, 64);
      r1 = KV[(size_t)s * 64 + lane];
    }
    for (int p = 0; p < cnt; p += 2) {
      uint4 c0 = r0, c1 = r1;
      float f0 = e0, f1 = e1;
      if (p + 2 < cnt) {
        int s = __shfl(sN, p + 2, 64);
        e0 = __shfl(eaN, p + 2, 64);
        r0 = KV[(size_t)s * 64 + lane];
      }
      if (p + 3 < cnt) {
        int s = __shfl(sN, p + 3, 64);
        e1 = __shfl(eaN, p + 3, 64);
        r1 = KV[(size_t)s * 64 + lane];
      }
      {  // state A <- edge p
        float k0 = bf2f(c0.x & 0xffffu), k1 = bf2f(c0.x >> 16);
        float k2 = bf2f(c0.y & 0xffffu), k3 = bf2f(c0.y >> 16);
        float v0 = bf2f(c0.z & 0xffffu), v1 = bf2f(c0.z >> 16);
        float v2 = bf2f(c0.w & 0xffffu), v3 = bf2f(c0.w >> 16);
        float d = q0 * fmaf(f0, we4.x, k0) + q1 * fmaf(f0, we4.y, k1) +
                  q2 * fmaf(f0, we4.z, k2) + q3 * fmaf(f0, we4.w, k3);
        d += __shfl_xor(d, 1, 64);
        d += __shfl_xor(d, 2, 64);
        d += __shfl_xor(d, 4, 64);
        d += __shfl_xor(d, 8, 64);
        float alpha = d * kScale;
        float mn = fmaxf(mA, alpha);
        float co = __expf(mA - mn);
        float pp = __expf(alpha - mn);
        lA = lA * co + pp;
        aA.x = fmaf(aA.x, co, pp * fmaf(f0, we4.x, v0));
        aA.y = fmaf(aA.y, co, pp * fmaf(f0, we4.y, v1));
        aA.z = fmaf(aA.z, co, pp * fmaf(f0, we4.z, v2));
        aA.w = fmaf(aA.w, co, pp * fmaf(f0, we4.w, v3));
        mA = mn;
      }
      if (p + 1 < cnt) {  // state B <- edge p+1
        float k0 = bf2f(c1.x & 0xffffu), k1 = bf2f(c1.x >> 16);
        float k2 = bf2f(c1.y & 0xffffu), k3 = bf2f(c1.y >> 16);
        float v0 = bf2f(c1.z & 0xffffu), v1 = bf2f(c1.z >> 16);
        float v2 = bf2f(c1.w & 0xffffu), v3 = bf2f(c1.w >> 16);
        float d = q0 * fmaf(f1, we4.x, k0) + q1 * fmaf(f1, we4.y, k1) +
                  q2 * fmaf(f1, we4.z, k2) + q3 * fmaf(f1, we4.w, k3);
        d += __shfl_xor(d, 1, 64);
        d += __shfl_xor(d, 2, 64);
        d += __shfl_xor(d, 4, 64);
        d += __shfl_xor(d, 8, 64);
        float alpha = d * kScale;
        float mn = fmaxf(mB, alpha);
        float co = __expf(mB - mn);
        float pp = __expf(alpha - mn);
        lB = lB * co + pp;
        aB.x = fmaf(aB.x, co, pp * fmaf(f1, we4.x, v0));
        aB.y = fmaf(aB.y, co, pp * fmaf(f1, we4.y, v1));
        aB.z = fmaf(aB.z, co, pp * fmaf(f1, we4.z, v2));
        aB.w = fmaf(aB.w, co, pp * fmaf(f1, we4.w, v3));
        mB = mn;
      }
    }
  }
  // merge B into A
  {
    float mn = fmaxf(mA, mB);
    float cA = __expf(mA - mn), cB = __expf(mB - mn);
    lA = lA * cA + lB * cB;
    aA.x = aA.x * cA + aB.x * cB;
    aA.y = aA.y * cA + aB.y * cB;
    aA.z = aA.z * cA + aB.z * cB;
    aA.w = aA.w * cA + aB.w * cB;
  }
  float inv = lA > 0.f ? 1.f / lA : 0.f;
  float4 o;
  o.x = aA.x * inv; o.y = aA.y * inv; o.z = aA.z * inv; o.w = aA.w * inv;

  // beta-gated skip
  float4 xr = ((const float4*)(Xr + (size_t)wid * 256))[lane];
  float4 wa = ((const float4*)Wb)[lane];
  float4 wbv = ((const float4*)(Wb + 256))[lane];
  float4 wc = ((const float4*)(Wb + 512))[lane];
  float t = o.x * (wa.x + wc.x) + o.y * (wa.y + wc.y) +
            o.z * (wa.z + wc.z) + o.w * (wa.w + wc.w) +
            xr.x * (wbv.x - wc.x) + xr.y * (wbv.y - wc.y) +
            xr.z * (wbv.z - wc.z) + xr.w * (wbv.w - wc.w);
#pragma unroll
  for (int o2 = 32; o2 >= 1; o2 >>= 1) t += __shfl_xor(t, o2, 64);
  float beta = 1.f / (1.f + __expf(-t));
  float4 h;
  h.x = beta * xr.x + (1.f - beta) * o.x;
  h.y = beta * xr.y + (1.f - beta) * o.y;
  h.z = beta * xr.z + (1.f - beta) * o.z;
  h.w = beta * xr.w + (1.f - beta) * o.w;
  ((float4*)(Hb + (size_t)wid * 256))[lane] = h;

  // BN partial sums: block-level LDS reduce then atomics
  ((float4*)&red[w][0])[lane] = h;
  __syncthreads();
  {
    float s = red[0][tid] + red[1][tid] + red[2][tid] + red[3][tid];
    atomicAdd(&bnsum[tid], s);
  }
  __syncthreads();
  float4 h2;
  h2.x = h.x * h.x; h2.y = h.y * h.y; h2.z = h.z * h.z; h2.w = h.w * h.w;
  ((float4*)&red[w][0])[lane] = h2;
  __syncthreads();
  {
    float s = red[0][tid] + red[1][tid] + red[2][tid] + red[3][tid];
    atomicAdd(&bnsq[tid], s);
  }
}

// ---------------------------------------------------------------- BN finalize + ELU -> bf16
// Optionally (gWp != null) also computes gate[n] and dec[n] (wave == node).
__global__ __launch_bounds__(256) void bn_elu_kernel(
    const float* __restrict__ Hb, const float* __restrict__ bnsum,
    const float* __restrict__ bnsq, const float* __restrict__ gma,
    const float* __restrict__ bta, __hip_bfloat16* __restrict__ H16,
    const float* __restrict__ gWp, const float* __restrict__ gBp,
    const float* __restrict__ dWp, float* __restrict__ gate,
    float* __restrict__ dec) {
  int idx = blockIdx.x * 256 + threadIdx.x;  // over kN*64 float4
  int d4 = idx & 63;
  int node = idx >> 6;
  float4 hv = ((const float4*)Hb)[idx];
  float4 s = ((const float4*)bnsum)[d4];
  float4 qq = ((const float4*)bnsq)[d4];
  float4 g = ((const float4*)gma)[d4];
  float4 b = ((const float4*)bta)[d4];
  const float inv_n = 1.f / (float)kN;
  auto f = [&](float h, float su, float sq, float ga, float be) {
    float mu = su * inv_n;
    float var = sq * inv_n - mu * mu;
    float y = ga * (h - mu) * rsqrtf(var + kEps) + be;
    return y > 0.f ? y : expm1f(y);
  };
  hv.x = f(hv.x, s.x, qq.x, g.x, b.x);
  hv.y = f(hv.y, s.y, qq.y, g.y, b.y);
  hv.z = f(hv.z, s.z, qq.z, g.z, b.z);
  hv.w = f(hv.w, s.w, qq.w, g.w, b.w);
  ushort4 rb;
  rb.x = f2bf(hv.x); rb.y = f2bf(hv.y); rb.z = f2bf(hv.z); rb.w = f2bf(hv.w);
  ((ushort4*)H16)[idx] = rb;
  if (gWp) {
    float4 gw = ((const float4*)gWp)[d4];
    float4 dw = ((const float4*)dWp)[d4];
    float tg = hv.x * gw.x + hv.y * gw.y + hv.z * gw.z + hv.w * gw.w;
    float td = hv.x * dw.x + hv.y * dw.y + hv.z * dw.z + hv.w * dw.w;
#pragma unroll
    for (int o = 32; o >= 1; o >>= 1) {
      tg += __shfl_xor(tg, o, 64);
      td += __shfl_xor(td, o, 64);
    }
    if (d4 == 0) {
      gate[node] = tg + gBp[0];
      dec[node] = td;
    }
  }
}

__device__ inline int lower_bound_dev(const int* a, int n, int key) {
  int lo = 0, hi = n;
  while (lo < hi) {
    int mid = (lo + hi) >> 1;
    if (a[mid] < key) lo = mid + 1; else hi = mid;
  }
  return lo;
}

// scalar segment-softmax pooling: out[g] = sum(a_n dec_n)/sum(a_n) + dB + oB
__global__ __launch_bounds__(256) void pool2_kernel(const float* __restrict__ gate,
                                                    const float* __restrict__ dec,
                                                    const int* __restrict__ batch,
                                                    const float* __restrict__ dB,
                                                    const float* __restrict__ oB,
                                                    float* __restrict__ out) {
  int g = blockIdx.x;
  int tid = threadIdx.x;
  int lane = tid & 63, w = tid >> 6;
  int lo = lower_bound_dev(batch, kN, g);
  int hi = lower_bound_dev(batch, kN, g + 1);
  float mx = -1e30f;
  for (int n = lo + tid; n < hi; n += 256) mx = fmaxf(mx, gate[n]);
#pragma unroll
  for (int o = 32; o >= 1; o >>= 1) mx = fmaxf(mx, __shfl_xor(mx, o, 64));
  __shared__ float sm[4];
  if (lane == 0) sm[w] = mx;
  __syncthreads();
  mx = fmaxf(fmaxf(sm[0], sm[1]), fmaxf(sm[2], sm[3]));
  float sn = 0.f, sd = 0.f;
  for (int n = lo + tid; n < hi; n += 256) {
    float a = __expf(gate[n] - mx);
    sn += a * dec[n];
    sd += a;
  }
#pragma unroll
  for (int o = 32; o >= 1; o >>= 1) {
    sn += __shfl_xor(sn, o, 64);
    sd += __shfl_xor(sd, o, 64);
  }
  __shared__ float s1[4], s2[4];
  if (lane == 0) { s1[w] = sn; s2[w] = sd; }
  __syncthreads();
  if (tid == 0) {
    float num = s1[0] + s1[1] + s1[2] + s1[3];
    float den = s2[0] + s2[1] + s2[2] + s2[3];
    out[g] = (den > 0.f ? num / den : 0.f) + dB[0] + oB[0];
  }
}

// ---------------------------------------------------------------- launch
extern "C" void kernel_launch(void* const* d_in, const int* in_sizes, int n_in,
                              void* d_out, int out_size, void* d_ws, size_t ws_size,
                              hipStream_t stream) {
  const float* x     = (const float*)d_in[0];
  const int*   ei    = (const int*)d_in[1];
  const float* eattr = (const float*)d_in[2];
  const int*   batch = (const int*)d_in[3];
  const float* encW  = (const float*)d_in[4];
  const float* encb  = (const float*)d_in[5];
  const float* Wq    = (const float*)d_in[6];
  const float* bq    = (const float*)d_in[7];
  const float* Wk    = (const float*)d_in[8];
  const float* bk    = (const float*)d_in[9];
  const float* Wv    = (const float*)d_in[10];
  const float* bv    = (const float*)d_in[11];
  const float* We    = (const float*)d_in[12];
  const float* Wsk   = (const float*)d_in[13];
  const float* bsk   = (const float*)d_in[14];
  const float* Wb    = (const float*)d_in[15];
  const float* bng   = (const float*)d_in[16];
  const float* bnb   = (const float*)d_in[17];
  const float* gW    = (const float*)d_in[18];
  const float* gB    = (const float*)d_in[19];
  const float* dW    = (const float*)d_in[20];
  const float* dB    = (const float*)d_in[21];
  const float* oB    = (const float*)d_in[22];
  float* out = (float*)d_out;

  char* base = (char*)d_ws;
  auto alloc = [&](size_t bytes) -> void* {
    void* p = (void*)base;
    base += (bytes + 255) & ~(size_t)255;
    return p;
  };
  float* hbuf   = (float*)alloc((size_t)kN * kD * 4);   // pre-BN h (fp32)
  float* xrbuf  = (float*)alloc((size_t)kN * kD * 4);
  unsigned short* q16buf = (unsigned short*)alloc((size_t)kN * kD * 2);
  unsigned short* kvbuf = (unsigned short*)alloc((size_t)kN * 512 * 2);  // interleaved bf16 K|V
  __hip_bfloat16* h16 = (__hip_bfloat16*)alloc((size_t)kN * kD * 2);
  __hip_bfloat16* wt16 = (__hip_bfloat16*)alloc((size_t)8 * 65536 * 2);
  float* gatebuf = (float*)alloc((size_t)kN * 4);
  float* decbuf  = (float*)alloc((size_t)kN * 4);
  int* rowst  = (int*)alloc((size_t)(kN + 1) * 4);
  int* cursor = (int*)alloc((size_t)kN * 4);
  int* counts = (int*)alloc((size_t)kN * 4);
  int* perm   = (int*)alloc((size_t)kE * 4);
  float* bnsum = (float*)alloc(2048);  // 256 sum + 256 sumsq contiguous
  float* bnsq = bnsum + 256;

  // edge sort by dst
  hipMemsetAsync(counts, 0, (size_t)kN * 4, stream);
  hist_kernel<<<kE / 256, 256, 0, stream>>>(ei, counts);
  scan_kernel<<<1, 1024, 0, stream>>>(counts, rowst, cursor);
  scatter_kernel<<<kE / 256, 256, 0, stream>>>(ei, cursor, perm);

  // weights -> transposed bf16 (once)
  transpose_w_kernel<<<dim3(8, 8, 8), 256, 0, stream>>>(Wq, Wk, Wv, Wsk, wt16);

  // encoder (bf16 h)
  enc_kernel<<<kN * 64 / 256, 256, 0, stream>>>(x, encW, encb, h16);

  for (int l = 0; l < 2; ++l) {
    size_t bo = (size_t)l * kD;
    gemm4_mfma<<<dim3(8, kN / 128), 256, 0, stream>>>(
        h16, wt16 + (size_t)l * 4 * 65536,
        bq + bo, bk + bo, bv + bo, bsk + bo,
        q16buf, kvbuf, xrbuf);
    hipMemsetAsync(bnsum, 0, 2048, stream);
    attn_fused_kernel<<<kN / 4, 256, 0, stream>>>(
        (const ushort4*)q16buf, (const uint4*)kvbuf, eattr, We + bo, ei, perm,
        rowst, xrbuf, Wb + (size_t)l * 768, hbuf, bnsum, bnsq);
    bool last = (l == 1);
    bn_elu_kernel<<<kN * 64 / 256, 256, 0, stream>>>(
        hbuf, bnsum, bnsq, bng + bo, bnb + bo, h16,
        last ? gW : nullptr, last ? gB : nullptr, last ? dW : nullptr,
        gatebuf, decbuf);
  }

  // readout
  pool2_kernel<<<kG, 256, 0, stream>>>(gatebuf, decbuf, batch, dB, oB, out);
}

// Round 6
// 407.115 us; speedup vs baseline: 1.7321x; 1.7321x over previous
//
#include <hip/hip_runtime.h>
#include <hip/hip_bf16.h>
#include <math.h>

// Problem constants (from reference setup_inputs)
constexpr int kN = 32768;   // nodes
constexpr int kE = 262144;  // edges
constexpr int kD = 256;     // hidden
constexpr int kH = 4;       // heads
constexpr int kC = 64;      // head dim
constexpr int kG = 32;      // graphs
constexpr float kScale = 0.125f;  // 1/sqrt(64)
constexpr float kEps = 1e-5f;

typedef __attribute__((ext_vector_type(8))) short short8;     // 8 bf16 = 4 VGPR
typedef __attribute__((ext_vector_type(4))) float floatx4;

__device__ inline unsigned short f2bf(float f) {
  union { __hip_bfloat16 b; unsigned short u; } cv;
  cv.b = __float2bfloat16(f);
  return cv.u;
}

__device__ inline float bf2f(unsigned int u16) {
  union { float f; unsigned int i; } c;
  c.i = u16 << 16;
  return c.f;
}

__device__ inline void async_copy16(const void* g, void* l) {
  __builtin_amdgcn_global_load_lds(
      (const __attribute__((address_space(1))) void*)g,
      (__attribute__((address_space(3))) void*)l, 16, 0, 0);
}

// ---------------------------------------------------------------- sort by dst
__global__ __launch_bounds__(256) void hist_kernel(const int* __restrict__ ei,
                                                   int* __restrict__ counts) {
  int e = blockIdx.x * 256 + threadIdx.x;
  atomicAdd(&counts[ei[kE + e]], 1);
}

__global__ __launch_bounds__(1024) void scan_kernel(const int* __restrict__ counts,
                                                    int* __restrict__ row_start,
                                                    int* __restrict__ cursor) {
  __shared__ int wsums[16];
  int t = threadIdx.x;
  int base_i = t * 32;
  int loc[32];
  int run = 0;
#pragma unroll
  for (int j = 0; j < 32; ++j) { loc[j] = run; run += counts[base_i + j]; }
  int incl = run;
  int lane = t & 63;
#pragma unroll
  for (int d = 1; d < 64; d <<= 1) {
    int v = __shfl_up(incl, d, 64);
    if (lane >= d) incl += v;
  }
  if (lane == 63) wsums[t >> 6] = incl;
  __syncthreads();
  if (t == 0) {
    int acc = 0;
    for (int w = 0; w < 16; ++w) { int tmp = wsums[w]; wsums[w] = acc; acc += tmp; }
  }
  __syncthreads();
  int base = wsums[t >> 6] + (incl - run);
#pragma unroll
  for (int j = 0; j < 32; ++j) {
    int v = base + loc[j];
    row_start[base_i + j] = v;
    cursor[base_i + j] = v;
  }
  if (t == 0) row_start[kN] = kE;
}

// scatter: write packed (src, edge_attr) at the dst-sorted position.
// Attention then needs ONE wave-uniform s_load_dwordx2 per edge instead of
// the 3-deep perm -> ei -> eattr dependent chain.
__global__ __launch_bounds__(256) void scatter_kernel(const int* __restrict__ ei,
                                                      const float* __restrict__ eattr,
                                                      int* __restrict__ cursor,
                                                      int2* __restrict__ sea) {
  int e = blockIdx.x * 256 + threadIdx.x;
  int d = ei[kE + e];
  int pos = atomicAdd(&cursor[d], 1);
  sea[pos] = make_int2(ei[e], __float_as_int(eattr[e]));
}

// ---------------------------------------------------------------- weight transpose + bf16
// Wt[slot][n][k] = W[slot][k][n] as bf16 ; slot = l*4 + {q,k,v,skip}
__global__ __launch_bounds__(256) void transpose_w_kernel(
    const float* __restrict__ Wq, const float* __restrict__ Wk,
    const float* __restrict__ Wv, const float* __restrict__ Ws,
    __hip_bfloat16* __restrict__ Wt) {
  __shared__ float T[32][33];
  int kt = blockIdx.x, nt = blockIdx.y, slot = blockIdx.z;
  int l = slot >> 2, mat = slot & 3;
  const float* src;
  if (mat == 0) src = Wq; else if (mat == 1) src = Wk;
  else if (mat == 2) src = Wv; else src = Ws;
  src += (size_t)l * 65536;
  int tid = threadIdx.x;
#pragma unroll
  for (int i = 0; i < 4; ++i) {
    int idx = tid + i * 256;
    int r = idx >> 5, c = idx & 31;
    T[r][c] = src[(size_t)(kt * 32 + r) * 256 + nt * 32 + c];
  }
  __syncthreads();
  __hip_bfloat16* dst = Wt + (size_t)slot * 65536;
#pragma unroll
  for (int i = 0; i < 4; ++i) {
    int idx = tid + i * 256;
    int r = idx >> 5, c = idx & 31;
    dst[(size_t)(nt * 32 + r) * 256 + kt * 32 + c] = __float2bfloat16(T[c][r]);
  }
}

// ---------------------------------------------------------------- encoder (bf16 only)
__global__ __launch_bounds__(256) void enc_kernel(const float* __restrict__ X,
                                                  const float* __restrict__ encW,
                                                  const float* __restrict__ encb,
                                                  __hip_bfloat16* __restrict__ H16) {
  int idx = blockIdx.x * 256 + threadIdx.x;  // over kN*64 float4
  int n = idx >> 6;
  int q = idx & 63;
  const float4* W4 = (const float4*)encW;
  float4 w0 = W4[q];
  float4 w1 = W4[64 + q];
  float4 bb = ((const float4*)encb)[q];
  float x0 = X[2 * n], x1 = X[2 * n + 1];
  float4 r;
  r.x = fmaf(x0, w0.x, fmaf(x1, w1.x, bb.x));
  r.y = fmaf(x0, w0.y, fmaf(x1, w1.y, bb.y));
  r.z = fmaf(x0, w0.z, fmaf(x1, w1.z, bb.z));
  r.w = fmaf(x0, w0.w, fmaf(x1, w1.w, bb.w));
  ushort4 rb;
  rb.x = f2bf(r.x); rb.y = f2bf(r.y); rb.z = f2bf(r.z); rb.w = f2bf(r.w);
  ((ushort4*)H16)[idx] = rb;
}

// ---------------------------------------------------------------- fused 4-GEMM (bf16 MFMA)
// Y = H @ W + b.  Q -> bf16 row buffer; Xr -> fp32; K,V -> interleaved bf16 KV:
// KV[node] is 1024B: chunk c (c=0..63) = { k[4c..4c+3] bf16, v[4c..4c+3] bf16 }.
__global__ __launch_bounds__(256) void gemm4_mfma(
    const __hip_bfloat16* __restrict__ H16,
    const __hip_bfloat16* __restrict__ Wt,  // 4 slots for this layer
    const float* __restrict__ bq, const float* __restrict__ bk,
    const float* __restrict__ bv, const float* __restrict__ bs,
    unsigned short* __restrict__ Q16, unsigned short* __restrict__ KV,
    float* __restrict__ Os) {
  int cb = blockIdx.x;           // 0..7 : (matrix, col-half)
  int m0 = blockIdx.y * 128;
  int wi = cb >> 1;
  int col0 = (cb & 1) * 128;
  const __hip_bfloat16* Wm = Wt + (size_t)wi * 65536;
  const float* bias;
  if (wi == 0)      bias = bq;
  else if (wi == 1) bias = bk;
  else if (wi == 2) bias = bv;
  else              bias = bs;

  __shared__ __align__(16) __hip_bfloat16 As[128 * 32];  // [m][k] row-major
  __shared__ __align__(16) __hip_bfloat16 Bs[128 * 32];  // [n][k] row-major

  int tid = threadIdx.x;
  int w = tid >> 6, lane = tid & 63;
  int wm = w & 1, wn = w >> 1;

  floatx4 acc[4][4];
#pragma unroll
  for (int i = 0; i < 4; ++i)
#pragma unroll
    for (int j = 0; j < 4; ++j) acc[i][j] = (floatx4){0.f, 0.f, 0.f, 0.f};

  int srow = lane >> 2;          // 0..15 (staging row within 16-row segment)
  int schunk = (lane & 3) * 8;   // 0,8,16,24 (bf16 elements)
  int arow = lane & 15, aq = lane >> 4;

  for (int kc = 0; kc < 256; kc += 32) {
#pragma unroll
    for (int t = 0; t < 2; ++t) {
      int s = w * 2 + t;  // segment 0..7 (16 rows each)
      const __hip_bfloat16* gA =
          H16 + (size_t)(m0 + s * 16 + srow) * 256 + kc + schunk;
      async_copy16(gA, (void*)(As + s * 512));
      const __hip_bfloat16* gB =
          Wm + (size_t)(col0 + s * 16 + srow) * 256 + kc + schunk;
      async_copy16(gB, (void*)(Bs + s * 512));
    }
    __syncthreads();
    short8 af[4], bf[4];
#pragma unroll
    for (int mi = 0; mi < 4; ++mi)
      af[mi] = *(const short8*)&As[(wm * 64 + mi * 16 + arow) * 32 + aq * 8];
#pragma unroll
    for (int ni = 0; ni < 4; ++ni)
      bf[ni] = *(const short8*)&Bs[(wn * 64 + ni * 16 + arow) * 32 + aq * 8];
#pragma unroll
    for (int mi = 0; mi < 4; ++mi)
#pragma unroll
      for (int ni = 0; ni < 4; ++ni)
        acc[mi][ni] = __builtin_amdgcn_mfma_f32_16x16x32_bf16(
            af[mi], bf[ni], acc[mi][ni], 0, 0, 0);
    __syncthreads();
  }

  // epilogue: C/D layout col=lane&15, row=(lane>>4)*4+reg
  int col = lane & 15, rq = (lane >> 4) * 4;
  if (wi == 3) {
#pragma unroll
    for (int ni = 0; ni < 4; ++ni) {
      int ccol = col0 + wn * 64 + ni * 16 + col;
      float bvv = bias[ccol];
#pragma unroll
      for (int mi = 0; mi < 4; ++mi) {
        int rbase = m0 + wm * 64 + mi * 16 + rq;
#pragma unroll
        for (int r = 0; r < 4; ++r)
          Os[(size_t)(rbase + r) * 256 + ccol] = acc[mi][ni][r] + bvv;
      }
    }
  } else if (wi == 0) {
#pragma unroll
    for (int ni = 0; ni < 4; ++ni) {
      int ccol = col0 + wn * 64 + ni * 16 + col;
      float bvv = bias[ccol];
#pragma unroll
      for (int mi = 0; mi < 4; ++mi) {
        int rbase = m0 + wm * 64 + mi * 16 + rq;
#pragma unroll
        for (int r = 0; r < 4; ++r)
          Q16[(size_t)(rbase + r) * 256 + ccol] = f2bf(acc[mi][ni][r] + bvv);
      }
    }
  } else {
    int off = (wi == 2) ? 4 : 0;  // K in first half of chunk, V in second
#pragma unroll
    for (int ni = 0; ni < 4; ++ni) {
      int ccol = col0 + wn * 64 + ni * 16 + col;
      float bvv = bias[ccol];
      size_t cofs = (size_t)(ccol >> 2) * 8 + off + (ccol & 3);
#pragma unroll
      for (int mi = 0; mi < 4; ++mi) {
        int rbase = m0 + wm * 64 + mi * 16 + rq;
#pragma unroll
        for (int r = 0; r < 4; ++r)
          KV[(size_t)(rbase + r) * 512 + cofs] = f2bf(acc[mi][ni][r] + bvv);
      }
    }
  }
}

// ---------------------------------------------------------------- fused attention + beta + BN stats
// one wave per dst node; lane L owns channels 4L..4L+3. ALL edge metadata is
// wave-uniform (single packed s_load_dwordx2 per edge); depth-2 prefetch with
// two interleaved softmax states. Epilogue: beta-gated skip, h write, BN
// partials into 16-way replicated atomic targets.
__global__ __launch_bounds__(256) void attn_fused_kernel(
    const ushort4* __restrict__ Q16,   // [N][64] bf16 quads
    const uint4* __restrict__ KV,
    const float* __restrict__ WeL,
    const int2* __restrict__ SEA,      // dst-sorted (src, edge_attr)
    const int* __restrict__ row_start,
    const float* __restrict__ Xr, const float* __restrict__ Wb,
    float* __restrict__ Hb, float* __restrict__ bnrep) {
  __shared__ float red[4][256];
  int tid = threadIdx.x;
  int w = tid >> 6, lane = tid & 63;
  int wid = blockIdx.x * 4 + w;

  ushort4 qr = Q16[(size_t)wid * 64 + lane];
  float q0 = bf2f(qr.x), q1 = bf2f(qr.y), q2 = bf2f(qr.z), q3 = bf2f(qr.w);
  float4 we4 = ((const float4*)WeL)[lane];
  int s0 = row_start[wid], s1 = row_start[wid + 1];

  float mA = -1e30f, lA = 0.f, mB = -1e30f, lB = 0.f;
  float4 aA = {0.f, 0.f, 0.f, 0.f}, aB = {0.f, 0.f, 0.f, 0.f};

  // depth-2 prefetch, all wave-uniform scalar loads
  uint4 r0 = {0, 0, 0, 0}, r1 = {0, 0, 0, 0};
  float e0 = 0.f, e1 = 0.f;
  if (s0 < s1) {
    int2 md = SEA[s0];
    e0 = __int_as_float(md.y);
    r0 = KV[(size_t)md.x * 64 + lane];
  }
  if (s0 + 1 < s1) {
    int2 md = SEA[s0 + 1];
    e1 = __int_as_float(md.y);
    r1 = KV[(size_t)md.x * 64 + lane];
  }
  for (int idx = s0; idx < s1; idx += 2) {
    uint4 c0 = r0, c1 = r1;
    float f0 = e0, f1 = e1;
    bool has1 = (idx + 1 < s1);
    if (idx + 2 < s1) {
      int2 md = SEA[idx + 2];
      e0 = __int_as_float(md.y);
      r0 = KV[(size_t)md.x * 64 + lane];
    }
    if (idx + 3 < s1) {
      int2 md = SEA[idx + 3];
      e1 = __int_as_float(md.y);
      r1 = KV[(size_t)md.x * 64 + lane];
    }
    {  // state A <- edge idx
      float k0 = bf2f(c0.x & 0xffffu), k1 = bf2f(c0.x >> 16);
      float k2 = bf2f(c0.y & 0xffffu), k3 = bf2f(c0.y >> 16);
      float v0 = bf2f(c0.z & 0xffffu), v1 = bf2f(c0.z >> 16);
      float v2 = bf2f(c0.w & 0xffffu), v3 = bf2f(c0.w >> 16);
      float d = q0 * fmaf(f0, we4.x, k0) + q1 * fmaf(f0, we4.y, k1) +
                q2 * fmaf(f0, we4.z, k2) + q3 * fmaf(f0, we4.w, k3);
      d += __shfl_xor(d, 1, 64);
      d += __shfl_xor(d, 2, 64);
      d += __shfl_xor(d, 4, 64);
      d += __shfl_xor(d, 8, 64);
      float alpha = d * kScale;
      float mn = fmaxf(mA, alpha);
      float co = __expf(mA - mn);
      float pp = __expf(alpha - mn);
      lA = lA * co + pp;
      aA.x = fmaf(aA.x, co, pp * fmaf(f0, we4.x, v0));
      aA.y = fmaf(aA.y, co, pp * fmaf(f0, we4.y, v1));
      aA.z = fmaf(aA.z, co, pp * fmaf(f0, we4.z, v2));
      aA.w = fmaf(aA.w, co, pp * fmaf(f0, we4.w, v3));
      mA = mn;
    }
    if (has1) {  // state B <- edge idx+1
      float k0 = bf2f(c1.x & 0xffffu), k1 = bf2f(c1.x >> 16);
      float k2 = bf2f(c1.y & 0xffffu), k3 = bf2f(c1.y >> 16);
      float v0 = bf2f(c1.z & 0xffffu), v1 = bf2f(c1.z >> 16);
      float v2 = bf2f(c1.w & 0xffffu), v3 = bf2f(c1.w >> 16);
      float d = q0 * fmaf(f1, we4.x, k0) + q1 * fmaf(f1, we4.y, k1) +
                q2 * fmaf(f1, we4.z, k2) + q3 * fmaf(f1, we4.w, k3);
      d += __shfl_xor(d, 1, 64);
      d += __shfl_xor(d, 2, 64);
      d += __shfl_xor(d, 4, 64);
      d += __shfl_xor(d, 8, 64);
      float alpha = d * kScale;
      float mn = fmaxf(mB, alpha);
      float co = __expf(mB - mn);
      float pp = __expf(alpha - mn);
      lB = lB * co + pp;
      aB.x = fmaf(aB.x, co, pp * fmaf(f1, we4.x, v0));
      aB.y = fmaf(aB.y, co, pp * fmaf(f1, we4.y, v1));
      aB.z = fmaf(aB.z, co, pp * fmaf(f1, we4.z, v2));
      aB.w = fmaf(aB.w, co, pp * fmaf(f1, we4.w, v3));
      mB = mn;
    }
  }
  // merge B into A
  {
    float mn = fmaxf(mA, mB);
    float cA = __expf(mA - mn), cB = __expf(mB - mn);
    lA = lA * cA + lB * cB;
    aA.x = aA.x * cA + aB.x * cB;
    aA.y = aA.y * cA + aB.y * cB;
    aA.z = aA.z * cA + aB.z * cB;
    aA.w = aA.w * cA + aB.w * cB;
  }
  float inv = lA > 0.f ? 1.f / lA : 0.f;
  float4 o;
  o.x = aA.x * inv; o.y = aA.y * inv; o.z = aA.z * inv; o.w = aA.w * inv;

  // beta-gated skip
  float4 xr = ((const float4*)(Xr + (size_t)wid * 256))[lane];
  float4 wa = ((const float4*)Wb)[lane];
  float4 wbv = ((const float4*)(Wb + 256))[lane];
  float4 wc = ((const float4*)(Wb + 512))[lane];
  float t = o.x * (wa.x + wc.x) + o.y * (wa.y + wc.y) +
            o.z * (wa.z + wc.z) + o.w * (wa.w + wc.w) +
            xr.x * (wbv.x - wc.x) + xr.y * (wbv.y - wc.y) +
            xr.z * (wbv.z - wc.z) + xr.w * (wbv.w - wc.w);
#pragma unroll
  for (int o2 = 32; o2 >= 1; o2 >>= 1) t += __shfl_xor(t, o2, 64);
  float beta = 1.f / (1.f + __expf(-t));
  float4 h;
  h.x = beta * xr.x + (1.f - beta) * o.x;
  h.y = beta * xr.y + (1.f - beta) * o.y;
  h.z = beta * xr.z + (1.f - beta) * o.z;
  h.w = beta * xr.w + (1.f - beta) * o.w;
  ((float4*)(Hb + (size_t)wid * 256))[lane] = h;

  // BN partial sums: block LDS reduce, then atomics into 16-way replicas
  float* rep = bnrep + (size_t)(blockIdx.x & 15) * 512;
  ((float4*)&red[w][0])[lane] = h;
  __syncthreads();
  {
    float s = red[0][tid] + red[1][tid] + red[2][tid] + red[3][tid];
    atomicAdd(&rep[tid], s);
  }
  __syncthreads();
  float4 h2;
  h2.x = h.x * h.x; h2.y = h.y * h.y; h2.z = h.z * h.z; h2.w = h.w * h.w;
  ((float4*)&red[w][0])[lane] = h2;
  __syncthreads();
  {
    float s = red[0][tid] + red[1][tid] + red[2][tid] + red[3][tid];
    atomicAdd(&rep[256 + tid], s);
  }
}

// reduce 16 replicas -> bnout[512] (sum 0..255, sumsq 256..511)
__global__ __launch_bounds__(512) void bn_reduce_kernel(const float* __restrict__ bnrep,
                                                        float* __restrict__ bnout) {
  int t = threadIdx.x;
  float s = 0.f;
#pragma unroll
  for (int r = 0; r < 16; ++r) s += bnrep[r * 512 + t];
  bnout[t] = s;
}

// ---------------------------------------------------------------- BN finalize + ELU -> bf16
// Optionally (gWp != null) also computes gate[n] and dec[n] (wave == node).
__global__ __launch_bounds__(256) void bn_elu_kernel(
    const float* __restrict__ Hb, const float* __restrict__ bnsum,
    const float* __restrict__ bnsq, const float* __restrict__ gma,
    const float* __restrict__ bta, __hip_bfloat16* __restrict__ H16,
    const float* __restrict__ gWp, const float* __restrict__ gBp,
    const float* __restrict__ dWp, float* __restrict__ gate,
    float* __restrict__ dec) {
  int idx = blockIdx.x * 256 + threadIdx.x;  // over kN*64 float4
  int d4 = idx & 63;
  int node = idx >> 6;
  float4 hv = ((const float4*)Hb)[idx];
  float4 s = ((const float4*)bnsum)[d4];
  float4 qq = ((const float4*)bnsq)[d4];
  float4 g = ((const float4*)gma)[d4];
  float4 b = ((const float4*)bta)[d4];
  const float inv_n = 1.f / (float)kN;
  auto f = [&](float h, float su, float sq, float ga, float be) {
    float mu = su * inv_n;
    float var = sq * inv_n - mu * mu;
    float y = ga * (h - mu) * rsqrtf(var + kEps) + be;
    return y > 0.f ? y : expm1f(y);
  };
  hv.x = f(hv.x, s.x, qq.x, g.x, b.x);
  hv.y = f(hv.y, s.y, qq.y, g.y, b.y);
  hv.z = f(hv.z, s.z, qq.z, g.z, b.z);
  hv.w = f(hv.w, s.w, qq.w, g.w, b.w);
  ushort4 rb;
  rb.x = f2bf(hv.x); rb.y = f2bf(hv.y); rb.z = f2bf(hv.z); rb.w = f2bf(hv.w);
  ((ushort4*)H16)[idx] = rb;
  if (gWp) {
    float4 gw = ((const float4*)gWp)[d4];
    float4 dw = ((const float4*)dWp)[d4];
    float tg = hv.x * gw.x + hv.y * gw.y + hv.z * gw.z + hv.w * gw.w;
    float td = hv.x * dw.x + hv.y * dw.y + hv.z * dw.z + hv.w * dw.w;
#pragma unroll
    for (int o = 32; o >= 1; o >>= 1) {
      tg += __shfl_xor(tg, o, 64);
      td += __shfl_xor(td, o, 64);
    }
    if (d4 == 0) {
      gate[node] = tg + gBp[0];
      dec[node] = td;
    }
  }
}

__device__ inline int lower_bound_dev(const int* a, int n, int key) {
  int lo = 0, hi = n;
  while (lo < hi) {
    int mid = (lo + hi) >> 1;
    if (a[mid] < key) lo = mid + 1; else hi = mid;
  }
  return lo;
}

// scalar segment-softmax pooling: out[g] = sum(a_n dec_n)/sum(a_n) + dB + oB
__global__ __launch_bounds__(256) void pool2_kernel(const float* __restrict__ gate,
                                                    const float* __restrict__ dec,
                                                    const int* __restrict__ batch,
                                                    const float* __restrict__ dB,
                                                    const float* __restrict__ oB,
                                                    float* __restrict__ out) {
  int g = blockIdx.x;
  int tid = threadIdx.x;
  int lane = tid & 63, w = tid >> 6;
  int lo = lower_bound_dev(batch, kN, g);
  int hi = lower_bound_dev(batch, kN, g + 1);
  float mx = -1e30f;
  for (int n = lo + tid; n < hi; n += 256) mx = fmaxf(mx, gate[n]);
#pragma unroll
  for (int o = 32; o >= 1; o >>= 1) mx = fmaxf(mx, __shfl_xor(mx, o, 64));
  __shared__ float sm[4];
  if (lane == 0) sm[w] = mx;
  __syncthreads();
  mx = fmaxf(fmaxf(sm[0], sm[1]), fmaxf(sm[2], sm[3]));
  float sn = 0.f, sd = 0.f;
  for (int n = lo + tid; n < hi; n += 256) {
    float a = __expf(gate[n] - mx);
    sn += a * dec[n];
    sd += a;
  }
#pragma unroll
  for (int o = 32; o >= 1; o >>= 1) {
    sn += __shfl_xor(sn, o, 64);
    sd += __shfl_xor(sd, o, 64);
  }
  __shared__ float s1[4], s2[4];
  if (lane == 0) { s1[w] = sn; s2[w] = sd; }
  __syncthreads();
  if (tid == 0) {
    float num = s1[0] + s1[1] + s1[2] + s1[3];
    float den = s2[0] + s2[1] + s2[2] + s2[3];
    out[g] = (den > 0.f ? num / den : 0.f) + dB[0] + oB[0];
  }
}

// ---------------------------------------------------------------- launch
extern "C" void kernel_launch(void* const* d_in, const int* in_sizes, int n_in,
                              void* d_out, int out_size, void* d_ws, size_t ws_size,
                              hipStream_t stream) {
  const float* x     = (const float*)d_in[0];
  const int*   ei    = (const int*)d_in[1];
  const float* eattr = (const float*)d_in[2];
  const int*   batch = (const int*)d_in[3];
  const float* encW  = (const float*)d_in[4];
  const float* encb  = (const float*)d_in[5];
  const float* Wq    = (const float*)d_in[6];
  const float* bq    = (const float*)d_in[7];
  const float* Wk    = (const float*)d_in[8];
  const float* bk    = (const float*)d_in[9];
  const float* Wv    = (const float*)d_in[10];
  const float* bv    = (const float*)d_in[11];
  const float* We    = (const float*)d_in[12];
  const float* Wsk   = (const float*)d_in[13];
  const float* bsk   = (const float*)d_in[14];
  const float* Wb    = (const float*)d_in[15];
  const float* bng   = (const float*)d_in[16];
  const float* bnb   = (const float*)d_in[17];
  const float* gW    = (const float*)d_in[18];
  const float* gB    = (const float*)d_in[19];
  const float* dW    = (const float*)d_in[20];
  const float* dB    = (const float*)d_in[21];
  const float* oB    = (const float*)d_in[22];
  float* out = (float*)d_out;

  char* base = (char*)d_ws;
  auto alloc = [&](size_t bytes) -> void* {
    void* p = (void*)base;
    base += (bytes + 255) & ~(size_t)255;
    return p;
  };
  float* hbuf   = (float*)alloc((size_t)kN * kD * 4);   // pre-BN h (fp32)
  float* xrbuf  = (float*)alloc((size_t)kN * kD * 4);
  unsigned short* q16buf = (unsigned short*)alloc((size_t)kN * kD * 2);
  unsigned short* kvbuf = (unsigned short*)alloc((size_t)kN * 512 * 2);  // interleaved bf16 K|V
  __hip_bfloat16* h16 = (__hip_bfloat16*)alloc((size_t)kN * kD * 2);
  __hip_bfloat16* wt16 = (__hip_bfloat16*)alloc((size_t)8 * 65536 * 2);
  float* gatebuf = (float*)alloc((size_t)kN * 4);
  float* decbuf  = (float*)alloc((size_t)kN * 4);
  int* rowst  = (int*)alloc((size_t)(kN + 1) * 4);
  int* cursor = (int*)alloc((size_t)kN * 4);
  int* counts = (int*)alloc((size_t)kN * 4);
  int2* seabuf = (int2*)alloc((size_t)kE * 8);          // dst-sorted (src, ea)
  float* bnrep = (float*)alloc((size_t)16 * 512 * 4);   // replicated BN partials
  float* bnout = (float*)alloc((size_t)512 * 4);        // reduced sum|sumsq

  // edge sort by dst
  hipMemsetAsync(counts, 0, (size_t)kN * 4, stream);
  hist_kernel<<<kE / 256, 256, 0, stream>>>(ei, counts);
  scan_kernel<<<1, 1024, 0, stream>>>(counts, rowst, cursor);
  scatter_kernel<<<kE / 256, 256, 0, stream>>>(ei, eattr, cursor, seabuf);

  // weights -> transposed bf16 (once)
  transpose_w_kernel<<<dim3(8, 8, 8), 256, 0, stream>>>(Wq, Wk, Wv, Wsk, wt16);

  // encoder (bf16 h)
  enc_kernel<<<kN * 64 / 256, 256, 0, stream>>>(x, encW, encb, h16);

  for (int l = 0; l < 2; ++l) {
    size_t bo = (size_t)l * kD;
    gemm4_mfma<<<dim3(8, kN / 128), 256, 0, stream>>>(
        h16, wt16 + (size_t)l * 4 * 65536,
        bq + bo, bk + bo, bv + bo, bsk + bo,
        q16buf, kvbuf, xrbuf);
    hipMemsetAsync(bnrep, 0, (size_t)16 * 512 * 4, stream);
    attn_fused_kernel<<<kN / 4, 256, 0, stream>>>(
        (const ushort4*)q16buf, (const uint4*)kvbuf, We + bo, seabuf,
        rowst, xrbuf, Wb + (size_t)l * 768, hbuf, bnrep);
    bn_reduce_kernel<<<1, 512, 0, stream>>>(bnrep, bnout);
    bool last = (l == 1);
    bn_elu_kernel<<<kN * 64 / 256, 256, 0, stream>>>(
        hbuf, bnout, bnout + 256, bng + bo, bnb + bo, h16,
        last ? gW : nullptr, last ? gB : nullptr, last ? dW : nullptr,
        gatebuf, decbuf);
  }

  // readout
  pool2_kernel<<<kG, 256, 0, stream>>>(gatebuf, decbuf, batch, dB, oB, out);
}

// Round 7
// 383.588 us; speedup vs baseline: 1.8383x; 1.0613x over previous
//
#include <hip/hip_runtime.h>
#include <hip/hip_bf16.h>
#include <math.h>

// Problem constants (from reference setup_inputs)
constexpr int kN = 32768;   // nodes
constexpr int kE = 262144;  // edges
constexpr int kD = 256;     // hidden
constexpr int kH = 4;       // heads
constexpr int kC = 64;      // head dim
constexpr int kG = 32;      // graphs
constexpr float kScale = 0.125f;  // 1/sqrt(64)
constexpr float kEps = 1e-5f;

typedef __attribute__((ext_vector_type(8))) short short8;     // 8 bf16 = 4 VGPR
typedef __attribute__((ext_vector_type(4))) float floatx4;

__device__ inline unsigned short f2bf(float f) {
  union { __hip_bfloat16 b; unsigned short u; } cv;
  cv.b = __float2bfloat16(f);
  return cv.u;
}

__device__ inline float bf2f(unsigned int u16) {
  union { float f; unsigned int i; } c;
  c.i = u16 << 16;
  return c.f;
}

__device__ inline void async_copy16(const void* g, void* l) {
  __builtin_amdgcn_global_load_lds(
      (const __attribute__((address_space(1))) void*)g,
      (__attribute__((address_space(3))) void*)l, 16, 0, 0);
}

// ---------------------------------------------------------------- fused prep
// blocks [0, 8192)        : encoder  x @ encW + encb -> H16 (bf16)
// blocks [8192, 9216)     : histogram of dst
// blocks [9216, 9728)     : weight transpose W[k][n] -> Wt[slot][n][k] bf16
__global__ __launch_bounds__(256) void prep_kernel(
    const float* __restrict__ X, const float* __restrict__ encW,
    const float* __restrict__ encb, __hip_bfloat16* __restrict__ H16,
    const int* __restrict__ ei, int* __restrict__ counts,
    const float* __restrict__ Wq, const float* __restrict__ Wk,
    const float* __restrict__ Wv, const float* __restrict__ Ws,
    __hip_bfloat16* __restrict__ Wt) {
  __shared__ float T[32][33];
  int bid = blockIdx.x;
  int tid = threadIdx.x;
  if (bid < 8192) {
    int idx = bid * 256 + tid;  // over kN*64 float4
    int n = idx >> 6;
    int q = idx & 63;
    const float4* W4 = (const float4*)encW;
    float4 w0 = W4[q];
    float4 w1 = W4[64 + q];
    float4 bb = ((const float4*)encb)[q];
    float x0 = X[2 * n], x1 = X[2 * n + 1];
    ushort4 rb;
    rb.x = f2bf(fmaf(x0, w0.x, fmaf(x1, w1.x, bb.x)));
    rb.y = f2bf(fmaf(x0, w0.y, fmaf(x1, w1.y, bb.y)));
    rb.z = f2bf(fmaf(x0, w0.z, fmaf(x1, w1.z, bb.z)));
    rb.w = f2bf(fmaf(x0, w0.w, fmaf(x1, w1.w, bb.w)));
    ((ushort4*)H16)[idx] = rb;
  } else if (bid < 9216) {
    int e = (bid - 8192) * 256 + tid;
    atomicAdd(&counts[ei[kE + e]], 1);
  } else {
    int s = bid - 9216;
    int kt = s & 7, nt = (s >> 3) & 7, slot = s >> 6;
    int l = slot >> 2, mat = slot & 3;
    const float* src;
    if (mat == 0) src = Wq; else if (mat == 1) src = Wk;
    else if (mat == 2) src = Wv; else src = Ws;
    src += (size_t)l * 65536;
#pragma unroll
    for (int i = 0; i < 4; ++i) {
      int idx = tid + i * 256;
      int r = idx >> 5, c = idx & 31;
      T[r][c] = src[(size_t)(kt * 32 + r) * 256 + nt * 32 + c];
    }
    __syncthreads();
    __hip_bfloat16* dst = Wt + (size_t)slot * 65536;
#pragma unroll
    for (int i = 0; i < 4; ++i) {
      int idx = tid + i * 256;
      int r = idx >> 5, c = idx & 31;
      dst[(size_t)(nt * 32 + r) * 256 + kt * 32 + c] = __float2bfloat16(T[c][r]);
    }
  }
}

__global__ __launch_bounds__(1024) void scan_kernel(const int* __restrict__ counts,
                                                    int* __restrict__ row_start,
                                                    int* __restrict__ cursor) {
  __shared__ int wsums[16];
  int t = threadIdx.x;
  int base_i = t * 32;
  int loc[32];
  int cv[32];
  const int4* c4 = (const int4*)counts;
#pragma unroll
  for (int j = 0; j < 8; ++j) {
    int4 v = c4[t * 8 + j];
    cv[j * 4 + 0] = v.x; cv[j * 4 + 1] = v.y;
    cv[j * 4 + 2] = v.z; cv[j * 4 + 3] = v.w;
  }
  int run = 0;
#pragma unroll
  for (int j = 0; j < 32; ++j) { loc[j] = run; run += cv[j]; }
  int incl = run;
  int lane = t & 63;
#pragma unroll
  for (int d = 1; d < 64; d <<= 1) {
    int v = __shfl_up(incl, d, 64);
    if (lane >= d) incl += v;
  }
  if (lane == 63) wsums[t >> 6] = incl;
  __syncthreads();
  if (t == 0) {
    int acc = 0;
    for (int w = 0; w < 16; ++w) { int tmp = wsums[w]; wsums[w] = acc; acc += tmp; }
  }
  __syncthreads();
  int base = wsums[t >> 6] + (incl - run);
#pragma unroll
  for (int j = 0; j < 32; ++j) {
    int v = base + loc[j];
    row_start[base_i + j] = v;
    cursor[base_i + j] = v;
  }
  if (t == 0) row_start[kN] = kE;
}

// scatter: write packed (src, edge_attr) at the dst-sorted position.
__global__ __launch_bounds__(256) void scatter_kernel(const int* __restrict__ ei,
                                                      const float* __restrict__ eattr,
                                                      int* __restrict__ cursor,
                                                      int2* __restrict__ sea) {
  int e = blockIdx.x * 256 + threadIdx.x;
  int d = ei[kE + e];
  int pos = atomicAdd(&cursor[d], 1);
  sea[pos] = make_int2(ei[e], __float_as_int(eattr[e]));
}

// ---------------------------------------------------------------- fused 4-GEMM (bf16 MFMA)
// Y = H @ W + b.  Q -> bf16 row buffer; Xr -> fp32; K,V -> interleaved bf16 KV:
// KV[node] is 1024B: chunk c (c=0..63) = { k[4c..4c+3] bf16, v[4c..4c+3] bf16 }.
// 1D grid, XCD-swizzled: cb = bid>>8 (matrix/col-half), m = bid&255, so all 8
// blocks sharing an A-tile have bid = m (mod 8) -> same XCD -> A from L2.
__global__ __launch_bounds__(256) void gemm4_mfma(
    const __hip_bfloat16* __restrict__ H16,
    const __hip_bfloat16* __restrict__ Wt,  // 4 slots for this layer
    const float* __restrict__ bq, const float* __restrict__ bk,
    const float* __restrict__ bv, const float* __restrict__ bs,
    unsigned short* __restrict__ Q16, unsigned short* __restrict__ KV,
    float* __restrict__ Os) {
  int bid = blockIdx.x;
  int cb = bid >> 8;             // 0..7 : (matrix, col-half)
  int m0 = (bid & 255) * 128;
  int wi = cb >> 1;
  int col0 = (cb & 1) * 128;
  const __hip_bfloat16* Wm = Wt + (size_t)wi * 65536;
  const float* bias;
  if (wi == 0)      bias = bq;
  else if (wi == 1) bias = bk;
  else if (wi == 2) bias = bv;
  else              bias = bs;

  __shared__ __align__(16) __hip_bfloat16 As[128 * 32];  // [m][k] row-major
  __shared__ __align__(16) __hip_bfloat16 Bs[128 * 32];  // [n][k] row-major

  int tid = threadIdx.x;
  int w = tid >> 6, lane = tid & 63;
  int wm = w & 1, wn = w >> 1;

  floatx4 acc[4][4];
#pragma unroll
  for (int i = 0; i < 4; ++i)
#pragma unroll
    for (int j = 0; j < 4; ++j) acc[i][j] = (floatx4){0.f, 0.f, 0.f, 0.f};

  int srow = lane >> 2;          // 0..15 (staging row within 16-row segment)
  int schunk = (lane & 3) * 8;   // 0,8,16,24 (bf16 elements)
  int arow = lane & 15, aq = lane >> 4;

  for (int kc = 0; kc < 256; kc += 32) {
#pragma unroll
    for (int t = 0; t < 2; ++t) {
      int s = w * 2 + t;  // segment 0..7 (16 rows each)
      const __hip_bfloat16* gA =
          H16 + (size_t)(m0 + s * 16 + srow) * 256 + kc + schunk;
      async_copy16(gA, (void*)(As + s * 512));
      const __hip_bfloat16* gB =
          Wm + (size_t)(col0 + s * 16 + srow) * 256 + kc + schunk;
      async_copy16(gB, (void*)(Bs + s * 512));
    }
    __syncthreads();
    short8 af[4], bf[4];
#pragma unroll
    for (int mi = 0; mi < 4; ++mi)
      af[mi] = *(const short8*)&As[(wm * 64 + mi * 16 + arow) * 32 + aq * 8];
#pragma unroll
    for (int ni = 0; ni < 4; ++ni)
      bf[ni] = *(const short8*)&Bs[(wn * 64 + ni * 16 + arow) * 32 + aq * 8];
#pragma unroll
    for (int mi = 0; mi < 4; ++mi)
#pragma unroll
      for (int ni = 0; ni < 4; ++ni)
        acc[mi][ni] = __builtin_amdgcn_mfma_f32_16x16x32_bf16(
            af[mi], bf[ni], acc[mi][ni], 0, 0, 0);
    __syncthreads();
  }

  // epilogue: C/D layout col=lane&15, row=(lane>>4)*4+reg
  int col = lane & 15, rq = (lane >> 4) * 4;
  if (wi == 3) {
#pragma unroll
    for (int ni = 0; ni < 4; ++ni) {
      int ccol = col0 + wn * 64 + ni * 16 + col;
      float bvv = bias[ccol];
#pragma unroll
      for (int mi = 0; mi < 4; ++mi) {
        int rbase = m0 + wm * 64 + mi * 16 + rq;
#pragma unroll
        for (int r = 0; r < 4; ++r)
          Os[(size_t)(rbase + r) * 256 + ccol] = acc[mi][ni][r] + bvv;
      }
    }
  } else if (wi == 0) {
#pragma unroll
    for (int ni = 0; ni < 4; ++ni) {
      int ccol = col0 + wn * 64 + ni * 16 + col;
      float bvv = bias[ccol];
#pragma unroll
      for (int mi = 0; mi < 4; ++mi) {
        int rbase = m0 + wm * 64 + mi * 16 + rq;
#pragma unroll
        for (int r = 0; r < 4; ++r)
          Q16[(size_t)(rbase + r) * 256 + ccol] = f2bf(acc[mi][ni][r] + bvv);
      }
    }
  } else {
    int off = (wi == 2) ? 4 : 0;  // K in first half of chunk, V in second
#pragma unroll
    for (int ni = 0; ni < 4; ++ni) {
      int ccol = col0 + wn * 64 + ni * 16 + col;
      float bvv = bias[ccol];
      size_t cofs = (size_t)(ccol >> 2) * 8 + off + (ccol & 3);
#pragma unroll
      for (int mi = 0; mi < 4; ++mi) {
        int rbase = m0 + wm * 64 + mi * 16 + rq;
#pragma unroll
        for (int r = 0; r < 4; ++r)
          KV[(size_t)(rbase + r) * 512 + cofs] = f2bf(acc[mi][ni][r] + bvv);
      }
    }
  }
}

// ---------------------------------------------------------------- fused attention + beta + BN stats
// one wave per dst node; lane L owns channels 4L..4L+3. Algebraic split:
//   q.(k+ea*we) = q.k + ea*(q.we)   -> qwe precomputed per node/head
//   sum w*(v+ea*we) = sum w*v + (sum w*ea)*we -> sea scalar accumulator
// All edge metadata wave-uniform (packed s_load per edge); depth-2 prefetch
// with two interleaved softmax states.
__global__ __launch_bounds__(256) void attn_fused_kernel(
    const ushort4* __restrict__ Q16,   // [N][64] bf16 quads
    const uint4* __restrict__ KV,
    const float* __restrict__ WeL,
    const int2* __restrict__ SEA,      // dst-sorted (src, edge_attr)
    const int* __restrict__ row_start,
    const float* __restrict__ Xr, const float* __restrict__ Wb,
    float* __restrict__ Hb, float* __restrict__ bnrep) {
  __shared__ float red[4][256];
  int tid = threadIdx.x;
  int w = tid >> 6, lane = tid & 63;
  int wid = blockIdx.x * 4 + w;

  ushort4 qr = Q16[(size_t)wid * 64 + lane];
  float q0 = bf2f(qr.x), q1 = bf2f(qr.y), q2 = bf2f(qr.z), q3 = bf2f(qr.w);
  float4 we4 = ((const float4*)WeL)[lane];
  float qwe = q0 * we4.x + q1 * we4.y + q2 * we4.z + q3 * we4.w;
  qwe += __shfl_xor(qwe, 1, 64);
  qwe += __shfl_xor(qwe, 2, 64);
  qwe += __shfl_xor(qwe, 4, 64);
  qwe += __shfl_xor(qwe, 8, 64);
  int s0 = row_start[wid], s1 = row_start[wid + 1];

  float mA = -1e30f, lA = 0.f, seaA = 0.f;
  float mB = -1e30f, lB = 0.f, seaB = 0.f;
  float4 aA = {0.f, 0.f, 0.f, 0.f}, aB = {0.f, 0.f, 0.f, 0.f};

  // depth-2 prefetch, all wave-uniform scalar loads
  uint4 r0 = {0, 0, 0, 0}, r1 = {0, 0, 0, 0};
  float e0 = 0.f, e1 = 0.f;
  if (s0 < s1) {
    int2 md = SEA[s0];
    e0 = __int_as_float(md.y);
    r0 = KV[(size_t)md.x * 64 + lane];
  }
  if (s0 + 1 < s1) {
    int2 md = SEA[s0 + 1];
    e1 = __int_as_float(md.y);
    r1 = KV[(size_t)md.x * 64 + lane];
  }
  for (int idx = s0; idx < s1; idx += 2) {
    uint4 c0 = r0, c1 = r1;
    float f0 = e0, f1 = e1;
    bool has1 = (idx + 1 < s1);
    if (idx + 2 < s1) {
      int2 md = SEA[idx + 2];
      e0 = __int_as_float(md.y);
      r0 = KV[(size_t)md.x * 64 + lane];
    }
    if (idx + 3 < s1) {
      int2 md = SEA[idx + 3];
      e1 = __int_as_float(md.y);
      r1 = KV[(size_t)md.x * 64 + lane];
    }
    {  // state A <- edge idx
      float k0 = bf2f(c0.x & 0xffffu), k1 = bf2f(c0.x >> 16);
      float k2 = bf2f(c0.y & 0xffffu), k3 = bf2f(c0.y >> 16);
      float d = q0 * k0 + q1 * k1 + q2 * k2 + q3 * k3;
      d += __shfl_xor(d, 1, 64);
      d += __shfl_xor(d, 2, 64);
      d += __shfl_xor(d, 4, 64);
      d += __shfl_xor(d, 8, 64);
      float alpha = fmaf(f0, qwe, d) * kScale;
      float mn = fmaxf(mA, alpha);
      float co = __expf(mA - mn);
      float pp = __expf(alpha - mn);
      lA = lA * co + pp;
      seaA = fmaf(seaA, co, pp * f0);
      float v0 = bf2f(c0.z & 0xffffu), v1 = bf2f(c0.z >> 16);
      float v2 = bf2f(c0.w & 0xffffu), v3 = bf2f(c0.w >> 16);
      aA.x = fmaf(aA.x, co, pp * v0);
      aA.y = fmaf(aA.y, co, pp * v1);
      aA.z = fmaf(aA.z, co, pp * v2);
      aA.w = fmaf(aA.w, co, pp * v3);
      mA = mn;
    }
    if (has1) {  // state B <- edge idx+1
      float k0 = bf2f(c1.x & 0xffffu), k1 = bf2f(c1.x >> 16);
      float k2 = bf2f(c1.y & 0xffffu), k3 = bf2f(c1.y >> 16);
      float d = q0 * k0 + q1 * k1 + q2 * k2 + q3 * k3;
      d += __shfl_xor(d, 1, 64);
      d += __shfl_xor(d, 2, 64);
      d += __shfl_xor(d, 4, 64);
      d += __shfl_xor(d, 8, 64);
      float alpha = fmaf(f1, qwe, d) * kScale;
      float mn = fmaxf(mB, alpha);
      float co = __expf(mB - mn);
      float pp = __expf(alpha - mn);
      lB = lB * co + pp;
      seaB = fmaf(seaB, co, pp * f1);
      float v0 = bf2f(c1.z & 0xffffu), v1 = bf2f(c1.z >> 16);
      float v2 = bf2f(c1.w & 0xffffu), v3 = bf2f(c1.w >> 16);
      aB.x = fmaf(aB.x, co, pp * v0);
      aB.y = fmaf(aB.y, co, pp * v1);
      aB.z = fmaf(aB.z, co, pp * v2);
      aB.w = fmaf(aB.w, co, pp * v3);
      mB = mn;
    }
  }
  // merge B into A
  {
    float mn = fmaxf(mA, mB);
    float cA = __expf(mA - mn), cB = __expf(mB - mn);
    lA = lA * cA + lB * cB;
    seaA = seaA * cA + seaB * cB;
    aA.x = aA.x * cA + aB.x * cB;
    aA.y = aA.y * cA + aB.y * cB;
    aA.z = aA.z * cA + aB.z * cB;
    aA.w = aA.w * cA + aB.w * cB;
  }
  float inv = lA > 0.f ? 1.f / lA : 0.f;
  float4 o;
  o.x = fmaf(seaA, we4.x, aA.x) * inv;
  o.y = fmaf(seaA, we4.y, aA.y) * inv;
  o.z = fmaf(seaA, we4.z, aA.z) * inv;
  o.w = fmaf(seaA, we4.w, aA.w) * inv;

  // beta-gated skip
  float4 xr = ((const float4*)(Xr + (size_t)wid * 256))[lane];
  float4 wa = ((const float4*)Wb)[lane];
  float4 wbv = ((const float4*)(Wb + 256))[lane];
  float4 wc = ((const float4*)(Wb + 512))[lane];
  float t = o.x * (wa.x + wc.x) + o.y * (wa.y + wc.y) +
            o.z * (wa.z + wc.z) + o.w * (wa.w + wc.w) +
            xr.x * (wbv.x - wc.x) + xr.y * (wbv.y - wc.y) +
            xr.z * (wbv.z - wc.z) + xr.w * (wbv.w - wc.w);
#pragma unroll
  for (int o2 = 32; o2 >= 1; o2 >>= 1) t += __shfl_xor(t, o2, 64);
  float beta = 1.f / (1.f + __expf(-t));
  float4 h;
  h.x = beta * xr.x + (1.f - beta) * o.x;
  h.y = beta * xr.y + (1.f - beta) * o.y;
  h.z = beta * xr.z + (1.f - beta) * o.z;
  h.w = beta * xr.w + (1.f - beta) * o.w;
  ((float4*)(Hb + (size_t)wid * 256))[lane] = h;

  // BN partial sums: block LDS reduce, then atomics into 16-way replicas
  float* rep = bnrep + (size_t)(blockIdx.x & 15) * 512;
  ((float4*)&red[w][0])[lane] = h;
  __syncthreads();
  {
    float s = red[0][tid] + red[1][tid] + red[2][tid] + red[3][tid];
    atomicAdd(&rep[tid], s);
  }
  __syncthreads();
  float4 h2;
  h2.x = h.x * h.x; h2.y = h.y * h.y; h2.z = h.z * h.z; h2.w = h.w * h.w;
  ((float4*)&red[w][0])[lane] = h2;
  __syncthreads();
  {
    float s = red[0][tid] + red[1][tid] + red[2][tid] + red[3][tid];
    atomicAdd(&rep[256 + tid], s);
  }
}

// reduce 16 replicas -> bnout[512] (sum 0..255, sumsq 256..511)
__global__ __launch_bounds__(512) void bn_reduce_kernel(const float* __restrict__ bnrep,
                                                        float* __restrict__ bnout) {
  int t = threadIdx.x;
  float s = 0.f;
#pragma unroll
  for (int r = 0; r < 16; ++r) s += bnrep[r * 512 + t];
  bnout[t] = s;
}

// ---------------------------------------------------------------- BN finalize + ELU -> bf16
// gWp == null : writes H16 (feeds next layer's GEMM).
// gWp != null : last layer — skips H16, computes gate[n], dec[n] instead.
__global__ __launch_bounds__(256) void bn_elu_kernel(
    const float* __restrict__ Hb, const float* __restrict__ bnsum,
    const float* __restrict__ bnsq, const float* __restrict__ gma,
    const float* __restrict__ bta, __hip_bfloat16* __restrict__ H16,
    const float* __restrict__ gWp, const float* __restrict__ gBp,
    const float* __restrict__ dWp, float* __restrict__ gate,
    float* __restrict__ dec) {
  int idx = blockIdx.x * 256 + threadIdx.x;  // over kN*64 float4
  int d4 = idx & 63;
  int node = idx >> 6;
  float4 hv = ((const float4*)Hb)[idx];
  float4 s = ((const float4*)bnsum)[d4];
  float4 qq = ((const float4*)bnsq)[d4];
  float4 g = ((const float4*)gma)[d4];
  float4 b = ((const float4*)bta)[d4];
  const float inv_n = 1.f / (float)kN;
  auto f = [&](float h, float su, float sq, float ga, float be) {
    float mu = su * inv_n;
    float var = sq * inv_n - mu * mu;
    float y = ga * (h - mu) * rsqrtf(var + kEps) + be;
    return y > 0.f ? y : expm1f(y);
  };
  hv.x = f(hv.x, s.x, qq.x, g.x, b.x);
  hv.y = f(hv.y, s.y, qq.y, g.y, b.y);
  hv.z = f(hv.z, s.z, qq.z, g.z, b.z);
  hv.w = f(hv.w, s.w, qq.w, g.w, b.w);
  if (!gWp) {
    ushort4 rb;
    rb.x = f2bf(hv.x); rb.y = f2bf(hv.y); rb.z = f2bf(hv.z); rb.w = f2bf(hv.w);
    ((ushort4*)H16)[idx] = rb;
  } else {
    float4 gw = ((const float4*)gWp)[d4];
    float4 dw = ((const float4*)dWp)[d4];
    float tg = hv.x * gw.x + hv.y * gw.y + hv.z * gw.z + hv.w * gw.w;
    float td = hv.x * dw.x + hv.y * dw.y + hv.z * dw.z + hv.w * dw.w;
#pragma unroll
    for (int o = 32; o >= 1; o >>= 1) {
      tg += __shfl_xor(tg, o, 64);
      td += __shfl_xor(td, o, 64);
    }
    if (d4 == 0) {
      gate[node] = tg + gBp[0];
      dec[node] = td;
    }
  }
}

__device__ inline int lower_bound_dev(const int* a, int n, int key) {
  int lo = 0, hi = n;
  while (lo < hi) {
    int mid = (lo + hi) >> 1;
    if (a[mid] < key) lo = mid + 1; else hi = mid;
  }
  return lo;
}

// scalar segment-softmax pooling: out[g] = sum(a_n dec_n)/sum(a_n) + dB + oB
__global__ __launch_bounds__(256) void pool2_kernel(const float* __restrict__ gate,
                                                    const float* __restrict__ dec,
                                                    const int* __restrict__ batch,
                                                    const float* __restrict__ dB,
                                                    const float* __restrict__ oB,
                                                    float* __restrict__ out) {
  int g = blockIdx.x;
  int tid = threadIdx.x;
  int lane = tid & 63, w = tid >> 6;
  int lo = lower_bound_dev(batch, kN, g);
  int hi = lower_bound_dev(batch, kN, g + 1);
  float mx = -1e30f;
  for (int n = lo + tid; n < hi; n += 256) mx = fmaxf(mx, gate[n]);
#pragma unroll
  for (int o = 32; o >= 1; o >>= 1) mx = fmaxf(mx, __shfl_xor(mx, o, 64));
  __shared__ float sm[4];
  if (lane == 0) sm[w] = mx;
  __syncthreads();
  mx = fmaxf(fmaxf(sm[0], sm[1]), fmaxf(sm[2], sm[3]));
  float sn = 0.f, sd = 0.f;
  for (int n = lo + tid; n < hi; n += 256) {
    float a = __expf(gate[n] - mx);
    sn += a * dec[n];
    sd += a;
  }
#pragma unroll
  for (int o = 32; o >= 1; o >>= 1) {
    sn += __shfl_xor(sn, o, 64);
    sd += __shfl_xor(sd, o, 64);
  }
  __shared__ float s1[4], s2[4];
  if (lane == 0) { s1[w] = sn; s2[w] = sd; }
  __syncthreads();
  if (tid == 0) {
    float num = s1[0] + s1[1] + s1[2] + s1[3];
    float den = s2[0] + s2[1] + s2[2] + s2[3];
    out[g] = (den > 0.f ? num / den : 0.f) + dB[0] + oB[0];
  }
}

// ---------------------------------------------------------------- launch
extern "C" void kernel_launch(void* const* d_in, const int* in_sizes, int n_in,
                              void* d_out, int out_size, void* d_ws, size_t ws_size,
                              hipStream_t stream) {
  const float* x     = (const float*)d_in[0];
  const int*   ei    = (const int*)d_in[1];
  const float* eattr = (const float*)d_in[2];
  const int*   batch = (const int*)d_in[3];
  const float* encW  = (const float*)d_in[4];
  const float* encb  = (const float*)d_in[5];
  const float* Wq    = (const float*)d_in[6];
  const float* bq    = (const float*)d_in[7];
  const float* Wk    = (const float*)d_in[8];
  const float* bk    = (const float*)d_in[9];
  const float* Wv    = (const float*)d_in[10];
  const float* bv    = (const float*)d_in[11];
  const float* We    = (const float*)d_in[12];
  const float* Wsk   = (const float*)d_in[13];
  const float* bsk   = (const float*)d_in[14];
  const float* Wb    = (const float*)d_in[15];
  const float* bng   = (const float*)d_in[16];
  const float* bnb   = (const float*)d_in[17];
  const float* gW    = (const float*)d_in[18];
  const float* gB    = (const float*)d_in[19];
  const float* dW    = (const float*)d_in[20];
  const float* dB    = (const float*)d_in[21];
  const float* oB    = (const float*)d_in[22];
  float* out = (float*)d_out;

  char* base = (char*)d_ws;
  auto alloc = [&](size_t bytes) -> void* {
    void* p = (void*)base;
    base += (bytes + 255) & ~(size_t)255;
    return p;
  };
  // counts + bnrep contiguous -> one memset clears both
  int* counts = (int*)alloc((size_t)kN * 4);            // 128 KB
  float* bnrep = (float*)alloc((size_t)2 * 16 * 512 * 4);  // 64 KB (2 layers)
  float* hbuf   = (float*)alloc((size_t)kN * kD * 4);   // pre-BN h (fp32)
  float* xrbuf  = (float*)alloc((size_t)kN * kD * 4);
  unsigned short* q16buf = (unsigned short*)alloc((size_t)kN * kD * 2);
  unsigned short* kvbuf = (unsigned short*)alloc((size_t)kN * 512 * 2);  // interleaved bf16 K|V
  __hip_bfloat16* h16 = (__hip_bfloat16*)alloc((size_t)kN * kD * 2);
  __hip_bfloat16* wt16 = (__hip_bfloat16*)alloc((size_t)8 * 65536 * 2);
  float* gatebuf = (float*)alloc((size_t)kN * 4);
  float* decbuf  = (float*)alloc((size_t)kN * 4);
  int* rowst  = (int*)alloc((size_t)(kN + 1) * 4);
  int* cursor = (int*)alloc((size_t)kN * 4);
  int2* seabuf = (int2*)alloc((size_t)kE * 8);          // dst-sorted (src, ea)
  float* bnout = (float*)alloc((size_t)512 * 4);        // reduced sum|sumsq

  // zero counts + both layers' BN replicas in one shot
  hipMemsetAsync(counts, 0, (size_t)kN * 4 + (size_t)2 * 16 * 512 * 4, stream);

  // fused: encoder + dst-histogram + weight transpose (independent work)
  prep_kernel<<<9728, 256, 0, stream>>>(x, encW, encb, h16, ei, counts,
                                        Wq, Wk, Wv, Wsk, wt16);
  scan_kernel<<<1, 1024, 0, stream>>>(counts, rowst, cursor);
  scatter_kernel<<<kE / 256, 256, 0, stream>>>(ei, eattr, cursor, seabuf);

  for (int l = 0; l < 2; ++l) {
    size_t bo = (size_t)l * kD;
    gemm4_mfma<<<2048, 256, 0, stream>>>(
        h16, wt16 + (size_t)l * 4 * 65536,
        bq + bo, bk + bo, bv + bo, bsk + bo,
        q16buf, kvbuf, xrbuf);
    float* brep = bnrep + (size_t)l * 16 * 512;
    attn_fused_kernel<<<kN / 4, 256, 0, stream>>>(
        (const ushort4*)q16buf, (const uint4*)kvbuf, We + bo, seabuf,
        rowst, xrbuf, Wb + (size_t)l * 768, hbuf, brep);
    bn_reduce_kernel<<<1, 512, 0, stream>>>(brep, bnout);
    bool last = (l == 1);
    bn_elu_kernel<<<kN * 64 / 256, 256, 0, stream>>>(
        hbuf, bnout, bnout + 256, bng + bo, bnb + bo, h16,
        last ? gW : nullptr, last ? gB : nullptr, last ? dW : nullptr,
        gatebuf, decbuf);
  }

  // readout
  pool2_kernel<<<kG, 256, 0, stream>>>(gatebuf, decbuf, batch, dB, oB, out);
}

// Round 8
// 372.704 us; speedup vs baseline: 1.8920x; 1.0292x over previous
//
#include <hip/hip_runtime.h>
#include <hip/hip_bf16.h>
#include <math.h>

// Problem constants (from reference setup_inputs)
constexpr int kN = 32768;   // nodes
constexpr int kE = 262144;  // edges
constexpr int kD = 256;     // hidden
constexpr int kH = 4;       // heads
constexpr int kC = 64;      // head dim
constexpr int kG = 32;      // graphs
constexpr float kScale = 0.125f;  // 1/sqrt(64)
constexpr float kEps = 1e-5f;

typedef __attribute__((ext_vector_type(8))) short short8;     // 8 bf16 = 4 VGPR
typedef __attribute__((ext_vector_type(4))) float floatx4;

__device__ inline unsigned short f2bf(float f) {
  union { __hip_bfloat16 b; unsigned short u; } cv;
  cv.b = __float2bfloat16(f);
  return cv.u;
}

__device__ inline float bf2f(unsigned int u16) {
  union { float f; unsigned int i; } c;
  c.i = u16 << 16;
  return c.f;
}

__device__ inline void async_copy16(const void* g, void* l) {
  __builtin_amdgcn_global_load_lds(
      (const __attribute__((address_space(1))) void*)g,
      (__attribute__((address_space(3))) void*)l, 16, 0, 0);
}

// ---------------------------------------------------------------- fused prep
// blocks [0, 8192)        : encoder  x @ encW + encb -> H16 (bf16)
// blocks [8192, 9216)     : histogram of dst
// blocks [9216, 9728)     : weight transpose W[k][n] -> Wt[slot][n][k] bf16
__global__ __launch_bounds__(256) void prep_kernel(
    const float* __restrict__ X, const float* __restrict__ encW,
    const float* __restrict__ encb, __hip_bfloat16* __restrict__ H16,
    const int* __restrict__ ei, int* __restrict__ counts,
    const float* __restrict__ Wq, const float* __restrict__ Wk,
    const float* __restrict__ Wv, const float* __restrict__ Ws,
    __hip_bfloat16* __restrict__ Wt) {
  __shared__ float T[32][33];
  int bid = blockIdx.x;
  int tid = threadIdx.x;
  if (bid < 8192) {
    int idx = bid * 256 + tid;  // over kN*64 float4
    int n = idx >> 6;
    int q = idx & 63;
    const float4* W4 = (const float4*)encW;
    float4 w0 = W4[q];
    float4 w1 = W4[64 + q];
    float4 bb = ((const float4*)encb)[q];
    float x0 = X[2 * n], x1 = X[2 * n + 1];
    ushort4 rb;
    rb.x = f2bf(fmaf(x0, w0.x, fmaf(x1, w1.x, bb.x)));
    rb.y = f2bf(fmaf(x0, w0.y, fmaf(x1, w1.y, bb.y)));
    rb.z = f2bf(fmaf(x0, w0.z, fmaf(x1, w1.z, bb.z)));
    rb.w = f2bf(fmaf(x0, w0.w, fmaf(x1, w1.w, bb.w)));
    ((ushort4*)H16)[idx] = rb;
  } else if (bid < 9216) {
    int e = (bid - 8192) * 256 + tid;
    atomicAdd(&counts[ei[kE + e]], 1);
  } else {
    int s = bid - 9216;
    int kt = s & 7, nt = (s >> 3) & 7, slot = s >> 6;
    int l = slot >> 2, mat = slot & 3;
    const float* src;
    if (mat == 0) src = Wq; else if (mat == 1) src = Wk;
    else if (mat == 2) src = Wv; else src = Ws;
    src += (size_t)l * 65536;
#pragma unroll
    for (int i = 0; i < 4; ++i) {
      int idx = tid + i * 256;
      int r = idx >> 5, c = idx & 31;
      T[r][c] = src[(size_t)(kt * 32 + r) * 256 + nt * 32 + c];
    }
    __syncthreads();
    __hip_bfloat16* dst = Wt + (size_t)slot * 65536;
#pragma unroll
    for (int i = 0; i < 4; ++i) {
      int idx = tid + i * 256;
      int r = idx >> 5, c = idx & 31;
      dst[(size_t)(nt * 32 + r) * 256 + kt * 32 + c] = __float2bfloat16(T[c][r]);
    }
  }
}

__global__ __launch_bounds__(1024) void scan_kernel(const int* __restrict__ counts,
                                                    int* __restrict__ row_start,
                                                    int* __restrict__ cursor) {
  __shared__ int wsums[16];
  int t = threadIdx.x;
  int base_i = t * 32;
  int loc[32];
  int cv[32];
  const int4* c4 = (const int4*)counts;
#pragma unroll
  for (int j = 0; j < 8; ++j) {
    int4 v = c4[t * 8 + j];
    cv[j * 4 + 0] = v.x; cv[j * 4 + 1] = v.y;
    cv[j * 4 + 2] = v.z; cv[j * 4 + 3] = v.w;
  }
  int run = 0;
#pragma unroll
  for (int j = 0; j < 32; ++j) { loc[j] = run; run += cv[j]; }
  int incl = run;
  int lane = t & 63;
#pragma unroll
  for (int d = 1; d < 64; d <<= 1) {
    int v = __shfl_up(incl, d, 64);
    if (lane >= d) incl += v;
  }
  if (lane == 63) wsums[t >> 6] = incl;
  __syncthreads();
  if (t == 0) {
    int acc = 0;
    for (int w = 0; w < 16; ++w) { int tmp = wsums[w]; wsums[w] = acc; acc += tmp; }
  }
  __syncthreads();
  int base = wsums[t >> 6] + (incl - run);
#pragma unroll
  for (int j = 0; j < 32; ++j) {
    int v = base + loc[j];
    row_start[base_i + j] = v;
    cursor[base_i + j] = v;
  }
  if (t == 0) row_start[kN] = kE;
}

// scatter: write packed (src, edge_attr) at the dst-sorted position.
__global__ __launch_bounds__(256) void scatter_kernel(const int* __restrict__ ei,
                                                      const float* __restrict__ eattr,
                                                      int* __restrict__ cursor,
                                                      int2* __restrict__ sea) {
  int e = blockIdx.x * 256 + threadIdx.x;
  int d = ei[kE + e];
  int pos = atomicAdd(&cursor[d], 1);
  sea[pos] = make_int2(ei[e], __float_as_int(eattr[e]));
}

// ---------------------------------------------------------------- fused 4-GEMM (bf16 MFMA)
// Y = H @ W + b.  Q -> bf16 row buffer; Xr -> fp32; K,V -> bf16 KV buffer:
// KV[node] is 1024B: shorts [0..255] = K row, [256..511] = V row (no
// interleave -> every 64B line is written contiguously by ONE block; the
// previous k|v interleave had cross-XCD half-line writes -> HBM RMW, +70MB).
// 1D grid, XCD-swizzled: cb = bid>>8 (matrix/col-half), m = bid&255, so all 8
// blocks sharing an A-tile have bid = m (mod 8) -> same XCD -> A from L2.
__global__ __launch_bounds__(256) void gemm4_mfma(
    const __hip_bfloat16* __restrict__ H16,
    const __hip_bfloat16* __restrict__ Wt,  // 4 slots for this layer
    const float* __restrict__ bq, const float* __restrict__ bk,
    const float* __restrict__ bv, const float* __restrict__ bs,
    unsigned short* __restrict__ Q16, unsigned short* __restrict__ KV,
    float* __restrict__ Os) {
  int bid = blockIdx.x;
  int cb = bid >> 8;             // 0..7 : (matrix, col-half)
  int m0 = (bid & 255) * 128;
  int wi = cb >> 1;
  int col0 = (cb & 1) * 128;
  const __hip_bfloat16* Wm = Wt + (size_t)wi * 65536;
  const float* bias;
  if (wi == 0)      bias = bq;
  else if (wi == 1) bias = bk;
  else if (wi == 2) bias = bv;
  else              bias = bs;

  __shared__ __align__(16) __hip_bfloat16 As[128 * 32];  // [m][k] row-major
  __shared__ __align__(16) __hip_bfloat16 Bs[128 * 32];  // [n][k] row-major

  int tid = threadIdx.x;
  int w = tid >> 6, lane = tid & 63;
  int wm = w & 1, wn = w >> 1;

  floatx4 acc[4][4];
#pragma unroll
  for (int i = 0; i < 4; ++i)
#pragma unroll
    for (int j = 0; j < 4; ++j) acc[i][j] = (floatx4){0.f, 0.f, 0.f, 0.f};

  int srow = lane >> 2;          // 0..15 (staging row within 16-row segment)
  int schunk = (lane & 3) * 8;   // 0,8,16,24 (bf16 elements)
  int arow = lane & 15, aq = lane >> 4;

  for (int kc = 0; kc < 256; kc += 32) {
#pragma unroll
    for (int t = 0; t < 2; ++t) {
      int s = w * 2 + t;  // segment 0..7 (16 rows each)
      const __hip_bfloat16* gA =
          H16 + (size_t)(m0 + s * 16 + srow) * 256 + kc + schunk;
      async_copy16(gA, (void*)(As + s * 512));
      const __hip_bfloat16* gB =
          Wm + (size_t)(col0 + s * 16 + srow) * 256 + kc + schunk;
      async_copy16(gB, (void*)(Bs + s * 512));
    }
    __syncthreads();
    short8 af[4], bf[4];
#pragma unroll
    for (int mi = 0; mi < 4; ++mi)
      af[mi] = *(const short8*)&As[(wm * 64 + mi * 16 + arow) * 32 + aq * 8];
#pragma unroll
    for (int ni = 0; ni < 4; ++ni)
      bf[ni] = *(const short8*)&Bs[(wn * 64 + ni * 16 + arow) * 32 + aq * 8];
#pragma unroll
    for (int mi = 0; mi < 4; ++mi)
#pragma unroll
      for (int ni = 0; ni < 4; ++ni)
        acc[mi][ni] = __builtin_amdgcn_mfma_f32_16x16x32_bf16(
            af[mi], bf[ni], acc[mi][ni], 0, 0, 0);
    __syncthreads();
  }

  // epilogue: C/D layout col=lane&15, row=(lane>>4)*4+reg
  int col = lane & 15, rq = (lane >> 4) * 4;
  if (wi == 3) {
#pragma unroll
    for (int ni = 0; ni < 4; ++ni) {
      int ccol = col0 + wn * 64 + ni * 16 + col;
      float bvv = bias[ccol];
#pragma unroll
      for (int mi = 0; mi < 4; ++mi) {
        int rbase = m0 + wm * 64 + mi * 16 + rq;
#pragma unroll
        for (int r = 0; r < 4; ++r)
          Os[(size_t)(rbase + r) * 256 + ccol] = acc[mi][ni][r] + bvv;
      }
    }
  } else if (wi == 0) {
#pragma unroll
    for (int ni = 0; ni < 4; ++ni) {
      int ccol = col0 + wn * 64 + ni * 16 + col;
      float bvv = bias[ccol];
#pragma unroll
      for (int mi = 0; mi < 4; ++mi) {
        int rbase = m0 + wm * 64 + mi * 16 + rq;
#pragma unroll
        for (int r = 0; r < 4; ++r)
          Q16[(size_t)(rbase + r) * 256 + ccol] = f2bf(acc[mi][ni][r] + bvv);
      }
    }
  } else {
    int off = (wi == 2) ? 256 : 0;  // K -> shorts [0..255], V -> [256..511]
#pragma unroll
    for (int ni = 0; ni < 4; ++ni) {
      int ccol = col0 + wn * 64 + ni * 16 + col;
      float bvv = bias[ccol];
#pragma unroll
      for (int mi = 0; mi < 4; ++mi) {
        int rbase = m0 + wm * 64 + mi * 16 + rq;
#pragma unroll
        for (int r = 0; r < 4; ++r)
          KV[(size_t)(rbase + r) * 512 + off + ccol] = f2bf(acc[mi][ni][r] + bvv);
      }
    }
  }
}

// ---------------------------------------------------------------- fused attention + beta + BN stats
// one wave per dst node; lane L owns channels 4L..4L+3. Algebraic split:
//   q.(k+ea*we) = q.k + ea*(q.we)   -> qwe precomputed per node/head
//   sum w*(v+ea*we) = sum w*v + (sum w*ea)*we -> sea scalar accumulator
// All edge metadata wave-uniform (packed s_load per edge); depth-2 prefetch
// with two interleaved softmax states; per edge: two independent 8B loads
// (k-quad, v-quad) from the de-interleaved KV rows.
__global__ __launch_bounds__(256) void attn_fused_kernel(
    const ushort4* __restrict__ Q16,   // [N][64] bf16 quads
    const unsigned short* __restrict__ KV,  // [N][512]: K | V halves
    const float* __restrict__ WeL,
    const int2* __restrict__ SEA,      // dst-sorted (src, edge_attr)
    const int* __restrict__ row_start,
    const float* __restrict__ Xr, const float* __restrict__ Wb,
    float* __restrict__ Hb, float* __restrict__ bnrep) {
  __shared__ float red[4][256];
  int tid = threadIdx.x;
  int w = tid >> 6, lane = tid & 63;
  int wid = blockIdx.x * 4 + w;

  ushort4 qr = Q16[(size_t)wid * 64 + lane];
  float q0 = bf2f(qr.x), q1 = bf2f(qr.y), q2 = bf2f(qr.z), q3 = bf2f(qr.w);
  float4 we4 = ((const float4*)WeL)[lane];
  float qwe = q0 * we4.x + q1 * we4.y + q2 * we4.z + q3 * we4.w;
  qwe += __shfl_xor(qwe, 1, 64);
  qwe += __shfl_xor(qwe, 2, 64);
  qwe += __shfl_xor(qwe, 4, 64);
  qwe += __shfl_xor(qwe, 8, 64);
  int s0 = row_start[wid], s1 = row_start[wid + 1];

  float mA = -1e30f, lA = 0.f, seaA = 0.f;
  float mB = -1e30f, lB = 0.f, seaB = 0.f;
  float4 aA = {0.f, 0.f, 0.f, 0.f}, aB = {0.f, 0.f, 0.f, 0.f};

  // depth-2 prefetch, all wave-uniform scalar loads
  uint2 k0r = {0, 0}, v0r = {0, 0}, k1r = {0, 0}, v1r = {0, 0};
  float e0 = 0.f, e1 = 0.f;
  if (s0 < s1) {
    int2 md = SEA[s0];
    e0 = __int_as_float(md.y);
    const uint2* p = (const uint2*)(KV + (size_t)md.x * 512);
    k0r = p[lane];
    v0r = p[64 + lane];
  }
  if (s0 + 1 < s1) {
    int2 md = SEA[s0 + 1];
    e1 = __int_as_float(md.y);
    const uint2* p = (const uint2*)(KV + (size_t)md.x * 512);
    k1r = p[lane];
    v1r = p[64 + lane];
  }
  for (int idx = s0; idx < s1; idx += 2) {
    uint2 ck0 = k0r, cv0 = v0r, ck1 = k1r, cv1 = v1r;
    float f0 = e0, f1 = e1;
    bool has1 = (idx + 1 < s1);
    if (idx + 2 < s1) {
      int2 md = SEA[idx + 2];
      e0 = __int_as_float(md.y);
      const uint2* p = (const uint2*)(KV + (size_t)md.x * 512);
      k0r = p[lane];
      v0r = p[64 + lane];
    }
    if (idx + 3 < s1) {
      int2 md = SEA[idx + 3];
      e1 = __int_as_float(md.y);
      const uint2* p = (const uint2*)(KV + (size_t)md.x * 512);
      k1r = p[lane];
      v1r = p[64 + lane];
    }
    {  // state A <- edge idx
      float k0 = bf2f(ck0.x & 0xffffu), k1 = bf2f(ck0.x >> 16);
      float k2 = bf2f(ck0.y & 0xffffu), k3 = bf2f(ck0.y >> 16);
      float d = q0 * k0 + q1 * k1 + q2 * k2 + q3 * k3;
      d += __shfl_xor(d, 1, 64);
      d += __shfl_xor(d, 2, 64);
      d += __shfl_xor(d, 4, 64);
      d += __shfl_xor(d, 8, 64);
      float alpha = fmaf(f0, qwe, d) * kScale;
      float mn = fmaxf(mA, alpha);
      float co = __expf(mA - mn);
      float pp = __expf(alpha - mn);
      lA = lA * co + pp;
      seaA = fmaf(seaA, co, pp * f0);
      float v0 = bf2f(cv0.x & 0xffffu), v1 = bf2f(cv0.x >> 16);
      float v2 = bf2f(cv0.y & 0xffffu), v3 = bf2f(cv0.y >> 16);
      aA.x = fmaf(aA.x, co, pp * v0);
      aA.y = fmaf(aA.y, co, pp * v1);
      aA.z = fmaf(aA.z, co, pp * v2);
      aA.w = fmaf(aA.w, co, pp * v3);
      mA = mn;
    }
    if (has1) {  // state B <- edge idx+1
      float k0 = bf2f(ck1.x & 0xffffu), k1 = bf2f(ck1.x >> 16);
      float k2 = bf2f(ck1.y & 0xffffu), k3 = bf2f(ck1.y >> 16);
      float d = q0 * k0 + q1 * k1 + q2 * k2 + q3 * k3;
      d += __shfl_xor(d, 1, 64);
      d += __shfl_xor(d, 2, 64);
      d += __shfl_xor(d, 4, 64);
      d += __shfl_xor(d, 8, 64);
      float alpha = fmaf(f1, qwe, d) * kScale;
      float mn = fmaxf(mB, alpha);
      float co = __expf(mB - mn);
      float pp = __expf(alpha - mn);
      lB = lB * co + pp;
      seaB = fmaf(seaB, co, pp * f1);
      float v0 = bf2f(cv1.x & 0xffffu), v1 = bf2f(cv1.x >> 16);
      float v2 = bf2f(cv1.y & 0xffffu), v3 = bf2f(cv1.y >> 16);
      aB.x = fmaf(aB.x, co, pp * v0);
      aB.y = fmaf(aB.y, co, pp * v1);
      aB.z = fmaf(aB.z, co, pp * v2);
      aB.w = fmaf(aB.w, co, pp * v3);
      mB = mn;
    }
  }
  // merge B into A
  {
    float mn = fmaxf(mA, mB);
    float cA = __expf(mA - mn), cB = __expf(mB - mn);
    lA = lA * cA + lB * cB;
    seaA = seaA * cA + seaB * cB;
    aA.x = aA.x * cA + aB.x * cB;
    aA.y = aA.y * cA + aB.y * cB;
    aA.z = aA.z * cA + aB.z * cB;
    aA.w = aA.w * cA + aB.w * cB;
  }
  float inv = lA > 0.f ? 1.f / lA : 0.f;
  float4 o;
  o.x = fmaf(seaA, we4.x, aA.x) * inv;
  o.y = fmaf(seaA, we4.y, aA.y) * inv;
  o.z = fmaf(seaA, we4.z, aA.z) * inv;
  o.w = fmaf(seaA, we4.w, aA.w) * inv;

  // beta-gated skip
  float4 xr = ((const float4*)(Xr + (size_t)wid * 256))[lane];
  float4 wa = ((const float4*)Wb)[lane];
  float4 wbv = ((const float4*)(Wb + 256))[lane];
  float4 wc = ((const float4*)(Wb + 512))[lane];
  float t = o.x * (wa.x + wc.x) + o.y * (wa.y + wc.y) +
            o.z * (wa.z + wc.z) + o.w * (wa.w + wc.w) +
            xr.x * (wbv.x - wc.x) + xr.y * (wbv.y - wc.y) +
            xr.z * (wbv.z - wc.z) + xr.w * (wbv.w - wc.w);
#pragma unroll
  for (int o2 = 32; o2 >= 1; o2 >>= 1) t += __shfl_xor(t, o2, 64);
  float beta = 1.f / (1.f + __expf(-t));
  float4 h;
  h.x = beta * xr.x + (1.f - beta) * o.x;
  h.y = beta * xr.y + (1.f - beta) * o.y;
  h.z = beta * xr.z + (1.f - beta) * o.z;
  h.w = beta * xr.w + (1.f - beta) * o.w;
  ((float4*)(Hb + (size_t)wid * 256))[lane] = h;

  // BN partial sums: block LDS reduce, then atomics into 16-way replicas
  float* rep = bnrep + (size_t)(blockIdx.x & 15) * 512;
  ((float4*)&red[w][0])[lane] = h;
  __syncthreads();
  {
    float s = red[0][tid] + red[1][tid] + red[2][tid] + red[3][tid];
    atomicAdd(&rep[tid], s);
  }
  __syncthreads();
  float4 h2;
  h2.x = h.x * h.x; h2.y = h.y * h.y; h2.z = h.z * h.z; h2.w = h.w * h.w;
  ((float4*)&red[w][0])[lane] = h2;
  __syncthreads();
  {
    float s = red[0][tid] + red[1][tid] + red[2][tid] + red[3][tid];
    atomicAdd(&rep[256 + tid], s);
  }
}

// reduce 16 replicas -> bnout[512] (sum 0..255, sumsq 256..511)
__global__ __launch_bounds__(512) void bn_reduce_kernel(const float* __restrict__ bnrep,
                                                        float* __restrict__ bnout) {
  int t = threadIdx.x;
  float s = 0.f;
#pragma unroll
  for (int r = 0; r < 16; ++r) s += bnrep[r * 512 + t];
  bnout[t] = s;
}

// ---------------------------------------------------------------- BN finalize + ELU -> bf16
// gWp == null : writes H16 (feeds next layer's GEMM).
// gWp != null : last layer — skips H16, computes gate[n], dec[n] instead.
__global__ __launch_bounds__(256) void bn_elu_kernel(
    const float* __restrict__ Hb, const float* __restrict__ bnsum,
    const float* __restrict__ bnsq, const float* __restrict__ gma,
    const float* __restrict__ bta, __hip_bfloat16* __restrict__ H16,
    const float* __restrict__ gWp, const float* __restrict__ gBp,
    const float* __restrict__ dWp, float* __restrict__ gate,
    float* __restrict__ dec) {
  int idx = blockIdx.x * 256 + threadIdx.x;  // over kN*64 float4
  int d4 = idx & 63;
  int node = idx >> 6;
  float4 hv = ((const float4*)Hb)[idx];
  float4 s = ((const float4*)bnsum)[d4];
  float4 qq = ((const float4*)bnsq)[d4];
  float4 g = ((const float4*)gma)[d4];
  float4 b = ((const float4*)bta)[d4];
  const float inv_n = 1.f / (float)kN;
  auto f = [&](float h, float su, float sq, float ga, float be) {
    float mu = su * inv_n;
    float var = sq * inv_n - mu * mu;
    float y = ga * (h - mu) * rsqrtf(var + kEps) + be;
    return y > 0.f ? y : expm1f(y);
  };
  hv.x = f(hv.x, s.x, qq.x, g.x, b.x);
  hv.y = f(hv.y, s.y, qq.y, g.y, b.y);
  hv.z = f(hv.z, s.z, qq.z, g.z, b.z);
  hv.w = f(hv.w, s.w, qq.w, g.w, b.w);
  if (!gWp) {
    ushort4 rb;
    rb.x = f2bf(hv.x); rb.y = f2bf(hv.y); rb.z = f2bf(hv.z); rb.w = f2bf(hv.w);
    ((ushort4*)H16)[idx] = rb;
  } else {
    float4 gw = ((const float4*)gWp)[d4];
    float4 dw = ((const float4*)dWp)[d4];
    float tg = hv.x * gw.x + hv.y * gw.y + hv.z * gw.z + hv.w * gw.w;
    float td = hv.x * dw.x + hv.y * dw.y + hv.z * dw.z + hv.w * dw.w;
#pragma unroll
    for (int o = 32; o >= 1; o >>= 1) {
      tg += __shfl_xor(tg, o, 64);
      td += __shfl_xor(td, o, 64);
    }
    if (d4 == 0) {
      gate[node] = tg + gBp[0];
      dec[node] = td;
    }
  }
}

__device__ inline int lower_bound_dev(const int* a, int n, int key) {
  int lo = 0, hi = n;
  while (lo < hi) {
    int mid = (lo + hi) >> 1;
    if (a[mid] < key) lo = mid + 1; else hi = mid;
  }
  return lo;
}

// scalar segment-softmax pooling: out[g] = sum(a_n dec_n)/sum(a_n) + dB + oB
__global__ __launch_bounds__(256) void pool2_kernel(const float* __restrict__ gate,
                                                    const float* __restrict__ dec,
                                                    const int* __restrict__ batch,
                                                    const float* __restrict__ dB,
                                                    const float* __restrict__ oB,
                                                    float* __restrict__ out) {
  int g = blockIdx.x;
  int tid = threadIdx.x;
  int lane = tid & 63, w = tid >> 6;
  int lo = lower_bound_dev(batch, kN, g);
  int hi = lower_bound_dev(batch, kN, g + 1);
  float mx = -1e30f;
  for (int n = lo + tid; n < hi; n += 256) mx = fmaxf(mx, gate[n]);
#pragma unroll
  for (int o = 32; o >= 1; o >>= 1) mx = fmaxf(mx, __shfl_xor(mx, o, 64));
  __shared__ float sm[4];
  if (lane == 0) sm[w] = mx;
  __syncthreads();
  mx = fmaxf(fmaxf(sm[0], sm[1]), fmaxf(sm[2], sm[3]));
  float sn = 0.f, sd = 0.f;
  for (int n = lo + tid; n < hi; n += 256) {
    float a = __expf(gate[n] - mx);
    sn += a * dec[n];
    sd += a;
  }
#pragma unroll
  for (int o = 32; o >= 1; o >>= 1) {
    sn += __shfl_xor(sn, o, 64);
    sd += __shfl_xor(sd, o, 64);
  }
  __shared__ float s1[4], s2[4];
  if (lane == 0) { s1[w] = sn; s2[w] = sd; }
  __syncthreads();
  if (tid == 0) {
    float num = s1[0] + s1[1] + s1[2] + s1[3];
    float den = s2[0] + s2[1] + s2[2] + s2[3];
    out[g] = (den > 0.f ? num / den : 0.f) + dB[0] + oB[0];
  }
}

// ---------------------------------------------------------------- launch
extern "C" void kernel_launch(void* const* d_in, const int* in_sizes, int n_in,
                              void* d_out, int out_size, void* d_ws, size_t ws_size,
                              hipStream_t stream) {
  const float* x     = (const float*)d_in[0];
  const int*   ei    = (const int*)d_in[1];
  const float* eattr = (const float*)d_in[2];
  const int*   batch = (const int*)d_in[3];
  const float* encW  = (const float*)d_in[4];
  const float* encb  = (const float*)d_in[5];
  const float* Wq    = (const float*)d_in[6];
  const float* bq    = (const float*)d_in[7];
  const float* Wk    = (const float*)d_in[8];
  const float* bk    = (const float*)d_in[9];
  const float* Wv    = (const float*)d_in[10];
  const float* bv    = (const float*)d_in[11];
  const float* We    = (const float*)d_in[12];
  const float* Wsk   = (const float*)d_in[13];
  const float* bsk   = (const float*)d_in[14];
  const float* Wb    = (const float*)d_in[15];
  const float* bng   = (const float*)d_in[16];
  const float* bnb   = (const float*)d_in[17];
  const float* gW    = (const float*)d_in[18];
  const float* gB    = (const float*)d_in[19];
  const float* dW    = (const float*)d_in[20];
  const float* dB    = (const float*)d_in[21];
  const float* oB    = (const float*)d_in[22];
  float* out = (float*)d_out;

  char* base = (char*)d_ws;
  auto alloc = [&](size_t bytes) -> void* {
    void* p = (void*)base;
    base += (bytes + 255) & ~(size_t)255;
    return p;
  };
  // counts + bnrep contiguous -> one memset clears both
  int* counts = (int*)alloc((size_t)kN * 4);            // 128 KB
  float* bnrep = (float*)alloc((size_t)2 * 16 * 512 * 4);  // 64 KB (2 layers)
  float* hbuf   = (float*)alloc((size_t)kN * kD * 4);   // pre-BN h (fp32)
  float* xrbuf  = (float*)alloc((size_t)kN * kD * 4);
  unsigned short* q16buf = (unsigned short*)alloc((size_t)kN * kD * 2);
  unsigned short* kvbuf = (unsigned short*)alloc((size_t)kN * 512 * 2);  // K|V bf16 halves
  __hip_bfloat16* h16 = (__hip_bfloat16*)alloc((size_t)kN * kD * 2);
  __hip_bfloat16* wt16 = (__hip_bfloat16*)alloc((size_t)8 * 65536 * 2);
  float* gatebuf = (float*)alloc((size_t)kN * 4);
  float* decbuf  = (float*)alloc((size_t)kN * 4);
  int* rowst  = (int*)alloc((size_t)(kN + 1) * 4);
  int* cursor = (int*)alloc((size_t)kN * 4);
  int2* seabuf = (int2*)alloc((size_t)kE * 8);          // dst-sorted (src, ea)
  float* bnout = (float*)alloc((size_t)512 * 4);        // reduced sum|sumsq

  // zero counts + both layers' BN replicas in one shot
  hipMemsetAsync(counts, 0, (size_t)kN * 4 + (size_t)2 * 16 * 512 * 4, stream);

  // fused: encoder + dst-histogram + weight transpose (independent work)
  prep_kernel<<<9728, 256, 0, stream>>>(x, encW, encb, h16, ei, counts,
                                        Wq, Wk, Wv, Wsk, wt16);
  scan_kernel<<<1, 1024, 0, stream>>>(counts, rowst, cursor);
  scatter_kernel<<<kE / 256, 256, 0, stream>>>(ei, eattr, cursor, seabuf);

  for (int l = 0; l < 2; ++l) {
    size_t bo = (size_t)l * kD;
    gemm4_mfma<<<2048, 256, 0, stream>>>(
        h16, wt16 + (size_t)l * 4 * 65536,
        bq + bo, bk + bo, bv + bo, bsk + bo,
        q16buf, kvbuf, xrbuf);
    float* brep = bnrep + (size_t)l * 16 * 512;
    attn_fused_kernel<<<kN / 4, 256, 0, stream>>>(
        (const ushort4*)q16buf, kvbuf, We + bo, seabuf,
        rowst, xrbuf, Wb + (size_t)l * 768, hbuf, brep);
    bn_reduce_kernel<<<1, 512, 0, stream>>>(brep, bnout);
    bool last = (l == 1);
    bn_elu_kernel<<<kN * 64 / 256, 256, 0, stream>>>(
        hbuf, bnout, bnout + 256, bng + bo, bnb + bo, h16,
        last ? gW : nullptr, last ? gB : nullptr, last ? dW : nullptr,
        gatebuf, decbuf);
  }

  // readout
  pool2_kernel<<<kG, 256, 0, stream>>>(gatebuf, decbuf, batch, dB, oB, out);
}